// Round 10
// baseline (209.505 us; speedup 1.0000x reference)
//
#include <hip/hip_runtime.h>

#define F_IN 128
#define HID  64
#define NCLS 16

#define BSHIFT 8            // 256 nodes per bucket
#define BNODES 256
#define NB_MAX 512          // max buckets (N<=128k)
#define CHUNK  8192         // edges per partition block (nchunks must be <=256 for col_scan)
#define CAP    8192         // max edges per bucket in LDS (mean 4352, 50+ sigma margin)
#define PADB   772          // per-bucket padding slack: 256 rows * 3 + 4 (base align)

typedef __attribute__((ext_vector_type(2))) float f32x2;
typedef __attribute__((ext_vector_type(8))) short bf16x8;
typedef __attribute__((ext_vector_type(4))) float f32x4;

// round-to-nearest-even fp32 -> bf16
__device__ __forceinline__ unsigned short f2bf(float f) {
    unsigned int u = __float_as_uint(f);
    u += 0x7FFFu + ((u >> 16) & 1u);
    return (unsigned short)(u >> 16);
}
// one dword = 2 packed bf16 -> f32x2 (2 VALU unpack + packed add)
// NOTE: do NOT replace with __builtin_amdgcn_fdot2_f32_bf16 — it compiles on
// gfx950 but produces wrong numerics (round-9 failure, absmax 0.57).
__device__ __forceinline__ f32x2 bfpair(unsigned int u) {
    f32x2 r;
    r.x = __uint_as_float(u << 16);
    r.y = __uint_as_float(u & 0xFFFF0000u);
    return r;
}

// ---------- pass 1: per-block bucket histogram (non-atomic global) + fused w1t ----------
// 1024 threads/block: 16 waves/CU (was 4) to hide edge-stream + LDS-atomic latency
__global__ __launch_bounds__(1024) void hist_w1t_kernel(const int* __restrict__ dst,
                                                        int* __restrict__ blk_hist,
                                                        const float* __restrict__ W1,
                                                        unsigned short* __restrict__ w1t,
                                                        unsigned short* __restrict__ h2b,
                                                        int E, int N, int NB, int nchunks) {
    int blk = blockIdx.x;
    int tid = threadIdx.x;
    if (blk == nchunks) {           // fused W1 -> bf16 transpose block
        for (int i = tid; i < F_IN * HID; i += 1024) {
            int k = i >> 6, n = i & 63;
            w1t[n * F_IN + k] = f2bf(W1[i]);
        }
        if (tid < NCLS) h2b[(size_t)N * NCLS + tid] = 0;   // zero sentinel row for agg2
        return;
    }
    __shared__ int hist[NB_MAX];
    for (int i = tid; i < NB; i += 1024) hist[i] = 0;
    __syncthreads();
    int cb = blk * CHUNK;
    #pragma unroll
    for (int k = 0; k < CHUNK / 4096; k++) {
        int e = cb + (k * 1024 + tid) * 4;
        if (e + 3 < E) {
            int4 d4 = *(const int4*)&dst[e];
            atomicAdd(&hist[d4.x >> BSHIFT], 1);
            atomicAdd(&hist[d4.y >> BSHIFT], 1);
            atomicAdd(&hist[d4.z >> BSHIFT], 1);
            atomicAdd(&hist[d4.w >> BSHIFT], 1);
        } else {
            for (int t = 0; t < 4; t++)
                if (e + t < E) atomicAdd(&hist[dst[e + t] >> BSHIFT], 1);
        }
    }
    __syncthreads();
    for (int i = tid; i < NB; i += 1024) blk_hist[(size_t)blk * NB + i] = hist[i];
}

// ---------- pass 2: fused column-reduce + scan (single block, 512 threads) ----------
__global__ __launch_bounds__(512) void bucket_scan(const int* __restrict__ blk_hist,
                                                   int* __restrict__ bucket_base,
                                                   int NB, int E, int nchunks) {
    __shared__ int s[512];
    int tid = threadIdx.x;
    int v = 0;
    if (tid < NB) {
        #pragma unroll 4
        for (int j = 0; j < nchunks; j++) v += blk_hist[(size_t)j * NB + tid];
    }
    s[tid] = v;
    __syncthreads();
    for (int off = 1; off < 512; off <<= 1) {
        int t = (tid >= off) ? s[tid - off] : 0;
        __syncthreads();
        s[tid] += t;
        __syncthreads();
    }
    if (tid < NB) bucket_base[tid] = s[tid] - v;
    if (tid == 0) bucket_base[NB] = E;
}

// ---------- pass 2c: per-bucket parallel column scan -> absolute per-chunk bases ----------
__global__ __launch_bounds__(256) void col_scan(int* __restrict__ blk_hist,
                                                const int* __restrict__ bucket_base,
                                                int NB, int nchunks) {
    __shared__ int s[256];
    int b = blockIdx.x;
    int tid = threadIdx.x;
    int v = (tid < nchunks) ? blk_hist[(size_t)tid * NB + b] : 0;
    s[tid] = v;
    __syncthreads();
    for (int off = 1; off < 256; off <<= 1) {
        int t = (tid >= off) ? s[tid - off] : 0;
        __syncthreads();
        s[tid] += t;
        __syncthreads();
    }
    if (tid < nchunks) blk_hist[(size_t)tid * NB + b] = s[tid] - v + bucket_base[b];
}

// ---------- pass 3: single-pass partition (LDS cursors, coalesced per-bucket runs) ----------
// 1024 threads/block (same CHUNK): 16 waves/CU for gather/scatter latency hiding
__global__ __launch_bounds__(1024) void scatter_kernel(const int* __restrict__ src,
                                                       const int* __restrict__ dst,
                                                       const int* __restrict__ blk_hist,
                                                       unsigned int* __restrict__ part,
                                                       int E, int NB) {
    __shared__ int cur[NB_MAX];
    int tid = threadIdx.x;
    int blk = blockIdx.x;
    for (int i = tid; i < NB; i += 1024) cur[i] = blk_hist[(size_t)blk * NB + i];
    __syncthreads();
    int cb = blk * CHUNK;
    #pragma unroll
    for (int k = 0; k < CHUNK / 4096; k++) {
        int e = cb + (k * 1024 + tid) * 4;
        if (e + 3 < E) {
            int4 d4 = *(const int4*)&dst[e];
            int4 s4 = *(const int4*)&src[e];
            int p0 = atomicAdd(&cur[d4.x >> BSHIFT], 1);
            part[p0] = ((unsigned int)(d4.x & (BNODES - 1)) << 24) | (unsigned int)s4.x;
            int p1 = atomicAdd(&cur[d4.y >> BSHIFT], 1);
            part[p1] = ((unsigned int)(d4.y & (BNODES - 1)) << 24) | (unsigned int)s4.y;
            int p2 = atomicAdd(&cur[d4.z >> BSHIFT], 1);
            part[p2] = ((unsigned int)(d4.z & (BNODES - 1)) << 24) | (unsigned int)s4.z;
            int p3 = atomicAdd(&cur[d4.w >> BSHIFT], 1);
            part[p3] = ((unsigned int)(d4.w & (BNODES - 1)) << 24) | (unsigned int)s4.w;
        } else {
            for (int t = 0; t < 4; t++)
                if (e + t < E) {
                    int d = dst[e + t];
                    int pos = atomicAdd(&cur[d >> BSHIFT], 1);
                    part[pos] = ((unsigned int)(d & (BNODES - 1)) << 24) | (unsigned int)src[e + t];
                }
        }
    }
}

// ---------- pass 4: per-bucket counting sort -> PADDED csr (rows 4-aligned, sentinel N) ----------
__global__ __launch_bounds__(256) void csr_build(const unsigned int* __restrict__ part,
                                                 const int* __restrict__ bucket_base,
                                                 int* __restrict__ csr_src,
                                                 int* __restrict__ row_ptr,
                                                 int* __restrict__ row_len,
                                                 float* __restrict__ dis,
                                                 int N) {
    __shared__ unsigned int eL[CAP];
    __shared__ unsigned int outL[CAP + PADB];
    __shared__ int cnt[BNODES];
    __shared__ int sc[BNODES];
    __shared__ int cur[BNODES];
    int tid = threadIdx.x;
    int b = blockIdx.x;
    int eB = bucket_base[b];
    int eN = bucket_base[b + 1] - eB;
    if (eN > CAP) eN = CAP;
    int pb = (eB + b * PADB + 3) & ~3;   // 4-aligned padded bucket base

    cnt[tid] = 0;
    __syncthreads();
    for (int i = tid; i < eN; i += 256) {
        unsigned int v = part[eB + i];
        eL[i] = v;
        atomicAdd(&cnt[v >> 24], 1);
    }
    // sentinel-init the padded output region (real edges overwrite below)
    for (int i = tid; i < eN + PADB; i += 256) outL[i] = (unsigned int)N;
    __syncthreads();
    int myc = cnt[tid];
    int pd = (myc + 3) & ~3;        // padded row length (multiple of 4)
    sc[tid] = pd;
    __syncthreads();
    for (int off = 1; off < 256; off <<= 1) {
        int t = (tid >= off) ? sc[tid - off] : 0;
        __syncthreads();
        sc[tid] += t;
        __syncthreads();
    }
    int excl = sc[tid] - pd;        // multiple of 4
    cur[tid] = excl;
    int gnode = b * BNODES + tid;
    if (gnode < N) {
        row_ptr[gnode] = pb + excl;  // 4-aligned: pb aligned + excl mult of 4
        row_len[gnode] = pd;
        float d = (float)myc;
        dis[gnode] = d > 0.0f ? rsqrtf(fmaxf(d, 1.0f)) : 0.0f;
    }
    __syncthreads();
    int pTot = sc[BNODES - 1];      // padded bucket total (<= eN + PADB)
    for (int i = tid; i < eN; i += 256) {
        unsigned int v = eL[i];
        int pos = atomicAdd(&cur[v >> 24], 1);
        outL[pos] = v & 0xFFFFFFu;
    }
    __syncthreads();
    for (int i = tid; i < pTot; i += 256)
        csr_src[pb + i] = (int)outL[i];
}

// ---------- gemm1 via MFMA bf16: 64 rows/block; also emits zeroed sentinel row N ----------
__global__ __launch_bounds__(256) void gemm1_kernel(
        const float* __restrict__ x, const unsigned short* __restrict__ w1t,
        const float* __restrict__ dis, unsigned short* __restrict__ h1b, int N) {
    __shared__ unsigned short xs[64][136];
    __shared__ unsigned short wsb[64][136];
    __shared__ float diss[64];
    int tid = threadIdx.x;
    int w = tid >> 6;
    int lane = tid & 63;
    int row0 = blockIdx.x * 64;

    #pragma unroll
    for (int it = 0; it < 8; it++) {
        int f = it * 256 + tid;
        int r = f >> 5, c = f & 31;
        float4 v = make_float4(0.f, 0.f, 0.f, 0.f);
        if (row0 + r < N) v = ((const float4*)x)[(size_t)(row0 + r) * 32 + c];
        unsigned int p0 = (unsigned int)f2bf(v.x) | ((unsigned int)f2bf(v.y) << 16);
        unsigned int p1 = (unsigned int)f2bf(v.z) | ((unsigned int)f2bf(v.w) << 16);
        *(uint2*)&xs[r][c * 4] = make_uint2(p0, p1);
    }
    #pragma unroll
    for (int it = 0; it < 4; it++) {
        int f = it * 256 + tid;
        int r = f >> 4, c = f & 15;
        *(uint4*)&wsb[r][c * 8] = ((const uint4*)w1t)[f];
    }
    if (tid < 64) diss[tid] = (row0 + tid < N) ? dis[row0 + tid] : 0.f;
    __syncthreads();

    int q = lane >> 4;
    int l15 = lane & 15;
    f32x4 acc[4] = {{0,0,0,0},{0,0,0,0},{0,0,0,0},{0,0,0,0}};
    bf16x8 a[4];
    #pragma unroll
    for (int kk = 0; kk < 4; kk++)
        a[kk] = *(const bf16x8*)&xs[w * 16 + l15][kk * 32 + q * 8];
    #pragma unroll
    for (int kk = 0; kk < 4; kk++) {
        #pragma unroll
        for (int ct = 0; ct < 4; ct++) {
            bf16x8 b = *(const bf16x8*)&wsb[ct * 16 + l15][kk * 32 + q * 8];
            acc[ct] = __builtin_amdgcn_mfma_f32_16x16x32_bf16(a[kk], b, acc[ct], 0, 0, 0);
        }
    }
    __syncthreads();
    #pragma unroll
    for (int ct = 0; ct < 4; ct++) {
        #pragma unroll
        for (int r = 0; r < 4; r++) {
            int m = w * 16 + q * 4 + r;
            xs[m][ct * 16 + l15] = f2bf(acc[ct][r] * diss[m]);
        }
    }
    __syncthreads();
    #pragma unroll
    for (int it = 0; it < 2; it++) {
        int f = it * 256 + tid;
        int r = f >> 3, c = f & 7;
        if (row0 + r < N + 1)   // row N written as zeros (diss=0) -> gather sentinel
            ((uint4*)&h1b[(size_t)(row0 + r) * HID])[c] = *(const uint4*)&xs[r][c * 8];
    }
}

// ---------- fused layer-1 agg + ReLU + W2 GEMM ----------
// 2 nodes/wave (half-wave each: 4 slots x 8 dim-lanes); padded CSR rows (4-aligned):
// 2 int4 index loads + 2 vector sentinel-selects + 8 independent 16B gathers per lane.
__global__ __launch_bounds__(256) void agg1_fused(
        const int* __restrict__ row_ptr, const int* __restrict__ row_len,
        const int* __restrict__ csr_src,
        const unsigned short* __restrict__ h1b, const float* __restrict__ dis,
        const float* __restrict__ b1, const float* __restrict__ W2,
        unsigned short* __restrict__ h2b, int N) {
    __shared__ float W2t[NCLS][HID + 4];   // transposed, padded row stride 68
    __shared__ float ts[8][HID];
    int tid = threadIdx.x;
    int w = tid >> 6;
    int lane = tid & 63;
    int half = lane >> 5;      // node within wave
    int hl = lane & 31;        // lane within half
    int sub = hl & 7;          // dims sub*8 .. sub*8+7 (16B)
    int slot = hl >> 3;        // edge slot 0..3 (each owns 2 int4 runs)
    int n = blockIdx.x * 8 + w * 2 + half;
    int nc = (n < N) ? n : 0;  // clamp so tail lanes still load safely

    // issue row_ptr/row_len/dis + vector index loads BEFORE LDS staging
    int start = row_ptr[nc];   // 4-aligned by construction
    int plen = row_len[nc];    // multiple of 4
    float dn = dis[nc];
    const int4* ip = (const int4*)(csr_src + start);
    int4 q0 = ip[2 * slot];
    int4 q1 = ip[2 * slot + 1];

    for (int i = tid; i < HID * NCLS; i += 256) W2t[i & 15][i >> 4] = W2[i];
    __syncthreads();
    if (n >= N) return;        // after the only __syncthreads (no barrier below)

    // vector sentinel-select: plen % 4 == 0, one compare covers a whole int4
    int e0 = slot * 8;
    if (e0 >= plen)     q0 = make_int4(N, N, N, N);
    if (e0 + 4 >= plen) q1 = make_int4(N, N, N, N);
    const unsigned short* hp = h1b + sub * 8;
    uint4 v0 = *(const uint4*)(hp + (unsigned)q0.x * HID);
    uint4 v1 = *(const uint4*)(hp + (unsigned)q0.y * HID);
    uint4 v2 = *(const uint4*)(hp + (unsigned)q0.z * HID);
    uint4 v3 = *(const uint4*)(hp + (unsigned)q0.w * HID);
    uint4 v4 = *(const uint4*)(hp + (unsigned)q1.x * HID);
    uint4 v5 = *(const uint4*)(hp + (unsigned)q1.y * HID);
    uint4 v6 = *(const uint4*)(hp + (unsigned)q1.z * HID);
    uint4 v7 = *(const uint4*)(hp + (unsigned)q1.w * HID);
    f32x2 a0 = (bfpair(v0.x) + bfpair(v1.x)) + (bfpair(v2.x) + bfpair(v3.x));
    f32x2 a1 = (bfpair(v0.y) + bfpair(v1.y)) + (bfpair(v2.y) + bfpair(v3.y));
    f32x2 a2 = (bfpair(v0.z) + bfpair(v1.z)) + (bfpair(v2.z) + bfpair(v3.z));
    f32x2 a3 = (bfpair(v0.w) + bfpair(v1.w)) + (bfpair(v2.w) + bfpair(v3.w));
    a0 += (bfpair(v4.x) + bfpair(v5.x)) + (bfpair(v6.x) + bfpair(v7.x));
    a1 += (bfpair(v4.y) + bfpair(v5.y)) + (bfpair(v6.y) + bfpair(v7.y));
    a2 += (bfpair(v4.z) + bfpair(v5.z)) + (bfpair(v6.z) + bfpair(v7.z));
    a3 += (bfpair(v4.w) + bfpair(v5.w)) + (bfpair(v6.w) + bfpair(v7.w));
    // residual for rare rows with plen > 32 (sentinel entries included, harmless)
    for (int i = 32 + slot; i < plen; i += 4) {
        int s = csr_src[start + i];
        uint4 v = *(const uint4*)(hp + (unsigned)s * HID);
        a0 += bfpair(v.x);
        a1 += bfpair(v.y);
        a2 += bfpair(v.z);
        a3 += bfpair(v.w);
    }
    // reduce across the 4 slots (lane bits 3,4 — stays within the half)
    #pragma unroll
    for (int m = 8; m <= 16; m <<= 1) {
        a0.x += __shfl_xor(a0.x, m, 64); a0.y += __shfl_xor(a0.y, m, 64);
        a1.x += __shfl_xor(a1.x, m, 64); a1.y += __shfl_xor(a1.y, m, 64);
        a2.x += __shfl_xor(a2.x, m, 64); a2.y += __shfl_xor(a2.y, m, 64);
        a3.x += __shfl_xor(a3.x, m, 64); a3.y += __shfl_xor(a3.y, m, 64);
    }
    if (slot == 0) {
        float4 bl = ((const float4*)b1)[sub * 2];
        float4 bh = ((const float4*)b1)[sub * 2 + 1];
        float4 r0, r1;
        r0.x = fmaxf(fmaf(dn, a0.x, bl.x), 0.f);
        r0.y = fmaxf(fmaf(dn, a0.y, bl.y), 0.f);
        r0.z = fmaxf(fmaf(dn, a1.x, bl.z), 0.f);
        r0.w = fmaxf(fmaf(dn, a1.y, bl.w), 0.f);
        r1.x = fmaxf(fmaf(dn, a2.x, bh.x), 0.f);
        r1.y = fmaxf(fmaf(dn, a2.y, bh.y), 0.f);
        r1.z = fmaxf(fmaf(dn, a3.x, bh.z), 0.f);
        r1.w = fmaxf(fmaf(dn, a3.y, bh.w), 0.f);
        *(float4*)&ts[w * 2 + half][sub * 8] = r0;
        *(float4*)&ts[w * 2 + half][sub * 8 + 4] = r1;
    }
    // wave-local LDS round-trip (same wave writes+reads; compiler inserts lgkmcnt)
    int q = hl >> 4, c = hl & 15;       // q: K-half 0/1, c: output class
    const float* tp = &ts[w * 2 + half][q * 32];
    const float* wp = &W2t[c][q * 32];
    float4 t0 = *(const float4*)tp,        t1 = *(const float4*)(tp + 4);
    float4 t2 = *(const float4*)(tp + 8),  t3 = *(const float4*)(tp + 12);
    float4 t4 = *(const float4*)(tp + 16), t5 = *(const float4*)(tp + 20);
    float4 t6 = *(const float4*)(tp + 24), t7 = *(const float4*)(tp + 28);
    float4 u0 = *(const float4*)wp,        u1 = *(const float4*)(wp + 4);
    float4 u2 = *(const float4*)(wp + 8),  u3 = *(const float4*)(wp + 12);
    float4 u4 = *(const float4*)(wp + 16), u5 = *(const float4*)(wp + 20);
    float4 u6 = *(const float4*)(wp + 24), u7 = *(const float4*)(wp + 28);
    float p = t0.x * u0.x + t0.y * u0.y + t0.z * u0.z + t0.w * u0.w
            + t1.x * u1.x + t1.y * u1.y + t1.z * u1.z + t1.w * u1.w
            + t2.x * u2.x + t2.y * u2.y + t2.z * u2.z + t2.w * u2.w
            + t3.x * u3.x + t3.y * u3.y + t3.z * u3.z + t3.w * u3.w
            + t4.x * u4.x + t4.y * u4.y + t4.z * u4.z + t4.w * u4.w
            + t5.x * u5.x + t5.y * u5.y + t5.z * u5.z + t5.w * u5.w
            + t6.x * u6.x + t6.y * u6.y + t6.z * u6.z + t6.w * u6.w
            + t7.x * u7.x + t7.y * u7.y + t7.z * u7.z + t7.w * u7.w;
    p += __shfl_xor(p, 16, 64);         // combine the two K-halves
    if (hl < 16) h2b[(unsigned)n * NCLS + c] = f2bf(p * dn);
}

// ---------- fused layer-2 agg + epilogue ----------
// 8 nodes/wave (8 lanes each: 4 slots x 2 dim-lanes), padded CSR + int4 index loads
__global__ __launch_bounds__(256) void agg2_fused(
        const int* __restrict__ row_ptr, const int* __restrict__ row_len,
        const int* __restrict__ csr_src,
        const unsigned short* __restrict__ h2b, const float* __restrict__ dis,
        const float* __restrict__ b2, float* __restrict__ out, int N) {
    int t = blockIdx.x * 256 + threadIdx.x;
    int lane = t & 63;
    int grp = lane >> 3;         // node within wave (0..7)
    int gl = lane & 7;
    int slot = gl >> 1;          // edge slot 0..3
    int sub = gl & 1;            // dims sub*8 .. sub*8+7
    int n = (t >> 6) * 8 + grp;
    if (n >= N) return;          // uniform within each 8-lane group
    int start = row_ptr[n];
    int plen = row_len[n];
    const int4* ip = (const int4*)(csr_src + start);
    int4 q0 = ip[2 * slot];
    int4 q1 = ip[2 * slot + 1];
    int e0 = slot * 8;
    if (e0 >= plen)     q0 = make_int4(N, N, N, N);
    if (e0 + 4 >= plen) q1 = make_int4(N, N, N, N);
    const unsigned short* hp = h2b + sub * 8;
    uint4 v0 = *(const uint4*)(hp + (unsigned)q0.x * NCLS);
    uint4 v1 = *(const uint4*)(hp + (unsigned)q0.y * NCLS);
    uint4 v2 = *(const uint4*)(hp + (unsigned)q0.z * NCLS);
    uint4 v3 = *(const uint4*)(hp + (unsigned)q0.w * NCLS);
    uint4 v4 = *(const uint4*)(hp + (unsigned)q1.x * NCLS);
    uint4 v5 = *(const uint4*)(hp + (unsigned)q1.y * NCLS);
    uint4 v6 = *(const uint4*)(hp + (unsigned)q1.z * NCLS);
    uint4 v7 = *(const uint4*)(hp + (unsigned)q1.w * NCLS);
    f32x2 a0 = (bfpair(v0.x) + bfpair(v1.x)) + (bfpair(v2.x) + bfpair(v3.x));
    f32x2 a1 = (bfpair(v0.y) + bfpair(v1.y)) + (bfpair(v2.y) + bfpair(v3.y));
    f32x2 a2 = (bfpair(v0.z) + bfpair(v1.z)) + (bfpair(v2.z) + bfpair(v3.z));
    f32x2 a3 = (bfpair(v0.w) + bfpair(v1.w)) + (bfpair(v2.w) + bfpair(v3.w));
    a0 += (bfpair(v4.x) + bfpair(v5.x)) + (bfpair(v6.x) + bfpair(v7.x));
    a1 += (bfpair(v4.y) + bfpair(v5.y)) + (bfpair(v6.y) + bfpair(v7.y));
    a2 += (bfpair(v4.z) + bfpair(v5.z)) + (bfpair(v6.z) + bfpair(v7.z));
    a3 += (bfpair(v4.w) + bfpair(v5.w)) + (bfpair(v6.w) + bfpair(v7.w));
    for (int i = 32 + slot; i < plen; i += 4) {
        int s = csr_src[start + i];
        uint4 v = *(const uint4*)(hp + (unsigned)s * NCLS);
        a0 += bfpair(v.x);
        a1 += bfpair(v.y);
        a2 += bfpair(v.z);
        a3 += bfpair(v.w);
    }
    // reduce across 4 slots (lane bits 1,2 — stays inside the 8-lane group)
    #pragma unroll
    for (int m = 2; m <= 4; m <<= 1) {
        a0.x += __shfl_xor(a0.x, m, 64); a0.y += __shfl_xor(a0.y, m, 64);
        a1.x += __shfl_xor(a1.x, m, 64); a1.y += __shfl_xor(a1.y, m, 64);
        a2.x += __shfl_xor(a2.x, m, 64); a2.y += __shfl_xor(a2.y, m, 64);
        a3.x += __shfl_xor(a3.x, m, 64); a3.y += __shfl_xor(a3.y, m, 64);
    }
    if (slot == 0) {
        float dn = dis[n];
        float4 bl = ((const float4*)b2)[sub * 2];
        float4 bh = ((const float4*)b2)[sub * 2 + 1];
        float4 o0, o1;
        o0.x = fmaf(dn, a0.x, bl.x); o0.y = fmaf(dn, a0.y, bl.y);
        o0.z = fmaf(dn, a1.x, bl.z); o0.w = fmaf(dn, a1.y, bl.w);
        o1.x = fmaf(dn, a2.x, bh.x); o1.y = fmaf(dn, a2.y, bh.y);
        o1.z = fmaf(dn, a3.x, bh.z); o1.w = fmaf(dn, a3.y, bh.w);
        float* op = out + (unsigned)n * NCLS + sub * 8;
        *(float4*)op = o0;
        *(float4*)(op + 4) = o1;
    }
}

extern "C" void kernel_launch(void* const* d_in, const int* in_sizes, int n_in,
                              void* d_out, int out_size, void* d_ws, size_t ws_size,
                              hipStream_t stream) {
    const float* x   = (const float*)d_in[0];
    const int*   src = (const int*)  d_in[1];
    const int*   dst = (const int*)  d_in[2];
    const float* W1  = (const float*)d_in[3];
    const float* b1  = (const float*)d_in[4];
    const float* W2  = (const float*)d_in[5];
    const float* b2  = (const float*)d_in[6];
    float* out = (float*)d_out;
    int E = in_sizes[1];
    int N = in_sizes[0] / F_IN;
    int NB = (N + BNODES - 1) >> BSHIFT;
    int nchunks = (E + CHUNK - 1) / CHUNK;   // 208 for E=1.7M (col_scan requires <=256)

    char* ws = (char*)d_ws;
    size_t off = 0;
    auto alloc = [&](size_t bytes) { size_t o = off; off = (off + bytes + 255) & ~(size_t)255; return (void*)(ws + o); };
    int*   bucket_base   = (int*)  alloc((size_t)(NB + 1) * 4);
    int*   blk_hist      = (int*)  alloc((size_t)nchunks * NB * 4);
    int*   row_ptr       = (int*)  alloc((size_t)(N + 1) * 4);
    int*   row_len       = (int*)  alloc((size_t)N * 4);
    int*   csr_src       = (int*)  alloc((size_t)(E + (size_t)NB * PADB + 64) * 4);  // padded CSR
    float* dis           = (float*)alloc((size_t)N * 4);
    unsigned short* w1t  = (unsigned short*)alloc((size_t)F_IN * HID * 2);
    unsigned short* h1b  = (unsigned short*)alloc((size_t)(N + 1) * HID * 2);  // +1 sentinel row
    unsigned short* h2b  = (unsigned short*)alloc((size_t)(N + 1) * NCLS * 2); // +1 sentinel row
    // part[] aliases h1b: dead before gemm1 writes h1b (E*4 = 6.8MB <= (N+1)*HID*2 = 12.8MB)
    unsigned int* part   = (unsigned int*)h1b;

    hist_w1t_kernel<<<nchunks + 1, 1024, 0, stream>>>(dst, blk_hist, W1, w1t, h2b, E, N, NB, nchunks);
    bucket_scan    <<<1, 512, 0, stream>>>(blk_hist, bucket_base, NB, E, nchunks);
    col_scan       <<<NB, 256, 0, stream>>>(blk_hist, bucket_base, NB, nchunks);
    scatter_kernel <<<nchunks, 1024, 0, stream>>>(src, dst, blk_hist, part, E, NB);
    csr_build      <<<NB, 256, 0, stream>>>(part, bucket_base, csr_src, row_ptr, row_len, dis, N);
    gemm1_kernel   <<<(N + 64) / 64, 256, 0, stream>>>(x, w1t, dis, h1b, N);  // +1 covers row N
    agg1_fused     <<<(N + 7) / 8, 256, 0, stream>>>(row_ptr, row_len, csr_src, h1b, dis, b1, W2, h2b, N);
    agg2_fused     <<<(N + 31) / 32, 256, 0, stream>>>(row_ptr, row_len, csr_src, h2b, dis, b2, out, N);
}

// Round 11
// 200.103 us; speedup vs baseline: 1.0470x; 1.0470x over previous
//
#include <hip/hip_runtime.h>

#define F_IN 128
#define HID  64
#define NCLS 16

#define BSHIFT 8            // 256 nodes per bucket
#define BNODES 256
#define NB_MAX 512          // max buckets (N<=128k)
#define CHUNK  8192         // edges per partition block
#define CAP    8192         // max edges per bucket in LDS (mean 4352, 50+ sigma margin)
#define PADB   772          // per-bucket padding slack: 256 rows * 3 + 4 (base align)

typedef __attribute__((ext_vector_type(2))) float f32x2;
typedef __attribute__((ext_vector_type(8))) short bf16x8;
typedef __attribute__((ext_vector_type(4))) float f32x4;

// round-to-nearest-even fp32 -> bf16
__device__ __forceinline__ unsigned short f2bf(float f) {
    unsigned int u = __float_as_uint(f);
    u += 0x7FFFu + ((u >> 16) & 1u);
    return (unsigned short)(u >> 16);
}
// one dword = 2 packed bf16 -> f32x2 (2 VALU unpack + packed add)
// NOTE: do NOT replace with __builtin_amdgcn_fdot2_f32_bf16 — it compiles on
// gfx950 but produces wrong numerics (round-9 failure, absmax 0.57).
__device__ __forceinline__ f32x2 bfpair(unsigned int u) {
    f32x2 r;
    r.x = __uint_as_float(u << 16);
    r.y = __uint_as_float(u & 0xFFFF0000u);
    return r;
}

// ---------- pass 1: per-block LDS bucket histogram -> global bucket_count + fused w1t ----------
// bucket_count zeroed by hipMemsetAsync before this launch.
__global__ __launch_bounds__(256) void hist_w1t_kernel(const int* __restrict__ dst,
                                                       int* __restrict__ bucket_count,
                                                       const float* __restrict__ W1,
                                                       unsigned short* __restrict__ w1t,
                                                       unsigned short* __restrict__ h2b,
                                                       int E, int N, int NB, int nchunks) {
    int blk = blockIdx.x;
    int tid = threadIdx.x;
    if (blk == nchunks) {           // fused W1 -> bf16 transpose block
        for (int i = tid; i < F_IN * HID; i += 256) {
            int k = i >> 6, n = i & 63;
            w1t[n * F_IN + k] = f2bf(W1[i]);
        }
        if (tid < NCLS) h2b[(size_t)N * NCLS + tid] = 0;   // zero sentinel row for agg2
        return;
    }
    __shared__ int hist[NB_MAX];
    for (int i = tid; i < NB; i += 256) hist[i] = 0;
    __syncthreads();
    int cb = blk * CHUNK;
    #pragma unroll
    for (int k = 0; k < CHUNK / 1024; k++) {
        int e = cb + (k * 256 + tid) * 4;
        if (e + 3 < E) {
            int4 d4 = *(const int4*)&dst[e];
            atomicAdd(&hist[d4.x >> BSHIFT], 1);
            atomicAdd(&hist[d4.y >> BSHIFT], 1);
            atomicAdd(&hist[d4.z >> BSHIFT], 1);
            atomicAdd(&hist[d4.w >> BSHIFT], 1);
        } else {
            for (int t = 0; t < 4; t++)
                if (e + t < E) atomicAdd(&hist[dst[e + t] >> BSHIFT], 1);
        }
    }
    __syncthreads();
    for (int i = tid; i < NB; i += 256) {
        int c = hist[i];
        if (c) atomicAdd(&bucket_count[i], c);   // 391 addrs x 208 blocks: cheap
    }
}

// ---------- pass 2: tiny single-block scan of bucket totals -> bases + cursors ----------
__global__ __launch_bounds__(512) void bucket_scan(const int* __restrict__ bucket_count,
                                                   int* __restrict__ bucket_base,
                                                   int* __restrict__ bucket_cursor,
                                                   int NB, int E) {
    __shared__ int s[512];
    int tid = threadIdx.x;
    int v = (tid < NB) ? bucket_count[tid] : 0;
    s[tid] = v;
    __syncthreads();
    for (int off = 1; off < 512; off <<= 1) {
        int t = (tid >= off) ? s[tid - off] : 0;
        __syncthreads();
        s[tid] += t;
        __syncthreads();
    }
    if (tid < NB) {
        int base = s[tid] - v;
        bucket_base[tid] = base;
        bucket_cursor[tid] = base;
    }
    if (tid == 0) bucket_base[NB] = E;
}

// ---------- pass 3: self-reserving partition (LDS re-hist + global range reservation) ----------
// Within-bucket order is arrival order (nondeterministic) — csr_build sorts by node anyway.
__global__ __launch_bounds__(256) void scatter_kernel(const int* __restrict__ src,
                                                      const int* __restrict__ dst,
                                                      int* __restrict__ bucket_cursor,
                                                      unsigned int* __restrict__ part,
                                                      int E, int NB) {
    __shared__ int cnt[NB_MAX];
    __shared__ int cur[NB_MAX];
    int tid = threadIdx.x;
    int blk = blockIdx.x;
    for (int i = tid; i < NB; i += 256) cnt[i] = 0;
    __syncthreads();
    int cb = blk * CHUNK;
    #pragma unroll
    for (int k = 0; k < CHUNK / 1024; k++) {   // pass A: count own chunk
        int e = cb + (k * 256 + tid) * 4;
        if (e + 3 < E) {
            int4 d4 = *(const int4*)&dst[e];
            atomicAdd(&cnt[d4.x >> BSHIFT], 1);
            atomicAdd(&cnt[d4.y >> BSHIFT], 1);
            atomicAdd(&cnt[d4.z >> BSHIFT], 1);
            atomicAdd(&cnt[d4.w >> BSHIFT], 1);
        } else {
            for (int t = 0; t < 4; t++)
                if (e + t < E) atomicAdd(&cnt[dst[e + t] >> BSHIFT], 1);
        }
    }
    __syncthreads();
    for (int i = tid; i < NB; i += 256) {       // reserve contiguous ranges
        int c = cnt[i];
        cur[i] = c ? atomicAdd(&bucket_cursor[i], c) : 0;
    }
    __syncthreads();
    #pragma unroll
    for (int k = 0; k < CHUNK / 1024; k++) {   // pass B: scatter (dst re-read is L2-hot)
        int e = cb + (k * 256 + tid) * 4;
        if (e + 3 < E) {
            int4 d4 = *(const int4*)&dst[e];
            int4 s4 = *(const int4*)&src[e];
            int p0 = atomicAdd(&cur[d4.x >> BSHIFT], 1);
            part[p0] = ((unsigned int)(d4.x & (BNODES - 1)) << 24) | (unsigned int)s4.x;
            int p1 = atomicAdd(&cur[d4.y >> BSHIFT], 1);
            part[p1] = ((unsigned int)(d4.y & (BNODES - 1)) << 24) | (unsigned int)s4.y;
            int p2 = atomicAdd(&cur[d4.z >> BSHIFT], 1);
            part[p2] = ((unsigned int)(d4.z & (BNODES - 1)) << 24) | (unsigned int)s4.z;
            int p3 = atomicAdd(&cur[d4.w >> BSHIFT], 1);
            part[p3] = ((unsigned int)(d4.w & (BNODES - 1)) << 24) | (unsigned int)s4.w;
        } else {
            for (int t = 0; t < 4; t++)
                if (e + t < E) {
                    int d = dst[e + t];
                    int pos = atomicAdd(&cur[d >> BSHIFT], 1);
                    part[pos] = ((unsigned int)(d & (BNODES - 1)) << 24) | (unsigned int)src[e + t];
                }
        }
    }
}

// ---------- pass 4: per-bucket counting sort -> PADDED csr (rows 4-aligned, sentinel N) ----------
__global__ __launch_bounds__(256) void csr_build(const unsigned int* __restrict__ part,
                                                 const int* __restrict__ bucket_base,
                                                 int* __restrict__ csr_src,
                                                 int* __restrict__ row_ptr,
                                                 int* __restrict__ row_len,
                                                 float* __restrict__ dis,
                                                 int N) {
    __shared__ unsigned int eL[CAP];
    __shared__ unsigned int outL[CAP + PADB];
    __shared__ int cnt[BNODES];
    __shared__ int sc[BNODES];
    __shared__ int cur[BNODES];
    int tid = threadIdx.x;
    int b = blockIdx.x;
    int eB = bucket_base[b];
    int eN = bucket_base[b + 1] - eB;
    if (eN > CAP) eN = CAP;
    int pb = (eB + b * PADB + 3) & ~3;   // 4-aligned padded bucket base

    cnt[tid] = 0;
    __syncthreads();
    for (int i = tid; i < eN; i += 256) {
        unsigned int v = part[eB + i];
        eL[i] = v;
        atomicAdd(&cnt[v >> 24], 1);
    }
    // sentinel-init the padded output region (real edges overwrite below)
    for (int i = tid; i < eN + PADB; i += 256) outL[i] = (unsigned int)N;
    __syncthreads();
    int myc = cnt[tid];
    int pd = (myc + 3) & ~3;        // padded row length (multiple of 4)
    sc[tid] = pd;
    __syncthreads();
    for (int off = 1; off < 256; off <<= 1) {
        int t = (tid >= off) ? sc[tid - off] : 0;
        __syncthreads();
        sc[tid] += t;
        __syncthreads();
    }
    int excl = sc[tid] - pd;        // multiple of 4
    cur[tid] = excl;
    int gnode = b * BNODES + tid;
    if (gnode < N) {
        row_ptr[gnode] = pb + excl;  // 4-aligned: pb aligned + excl mult of 4
        row_len[gnode] = pd;
        float d = (float)myc;
        dis[gnode] = d > 0.0f ? rsqrtf(fmaxf(d, 1.0f)) : 0.0f;
    }
    __syncthreads();
    int pTot = sc[BNODES - 1];      // padded bucket total (<= eN + PADB)
    for (int i = tid; i < eN; i += 256) {
        unsigned int v = eL[i];
        int pos = atomicAdd(&cur[v >> 24], 1);
        outL[pos] = v & 0xFFFFFFu;
    }
    __syncthreads();
    for (int i = tid; i < pTot; i += 256)
        csr_src[pb + i] = (int)outL[i];
}

// ---------- gemm1 via MFMA bf16: 64 rows/block; also emits zeroed sentinel row N ----------
__global__ __launch_bounds__(256) void gemm1_kernel(
        const float* __restrict__ x, const unsigned short* __restrict__ w1t,
        const float* __restrict__ dis, unsigned short* __restrict__ h1b, int N) {
    __shared__ unsigned short xs[64][136];
    __shared__ unsigned short wsb[64][136];
    __shared__ float diss[64];
    int tid = threadIdx.x;
    int w = tid >> 6;
    int lane = tid & 63;
    int row0 = blockIdx.x * 64;

    #pragma unroll
    for (int it = 0; it < 8; it++) {
        int f = it * 256 + tid;
        int r = f >> 5, c = f & 31;
        float4 v = make_float4(0.f, 0.f, 0.f, 0.f);
        if (row0 + r < N) v = ((const float4*)x)[(size_t)(row0 + r) * 32 + c];
        unsigned int p0 = (unsigned int)f2bf(v.x) | ((unsigned int)f2bf(v.y) << 16);
        unsigned int p1 = (unsigned int)f2bf(v.z) | ((unsigned int)f2bf(v.w) << 16);
        *(uint2*)&xs[r][c * 4] = make_uint2(p0, p1);
    }
    #pragma unroll
    for (int it = 0; it < 4; it++) {
        int f = it * 256 + tid;
        int r = f >> 4, c = f & 15;
        *(uint4*)&wsb[r][c * 8] = ((const uint4*)w1t)[f];
    }
    if (tid < 64) diss[tid] = (row0 + tid < N) ? dis[row0 + tid] : 0.f;
    __syncthreads();

    int q = lane >> 4;
    int l15 = lane & 15;
    f32x4 acc[4] = {{0,0,0,0},{0,0,0,0},{0,0,0,0},{0,0,0,0}};
    bf16x8 a[4];
    #pragma unroll
    for (int kk = 0; kk < 4; kk++)
        a[kk] = *(const bf16x8*)&xs[w * 16 + l15][kk * 32 + q * 8];
    #pragma unroll
    for (int kk = 0; kk < 4; kk++) {
        #pragma unroll
        for (int ct = 0; ct < 4; ct++) {
            bf16x8 b = *(const bf16x8*)&wsb[ct * 16 + l15][kk * 32 + q * 8];
            acc[ct] = __builtin_amdgcn_mfma_f32_16x16x32_bf16(a[kk], b, acc[ct], 0, 0, 0);
        }
    }
    __syncthreads();
    #pragma unroll
    for (int ct = 0; ct < 4; ct++) {
        #pragma unroll
        for (int r = 0; r < 4; r++) {
            int m = w * 16 + q * 4 + r;
            xs[m][ct * 16 + l15] = f2bf(acc[ct][r] * diss[m]);
        }
    }
    __syncthreads();
    #pragma unroll
    for (int it = 0; it < 2; it++) {
        int f = it * 256 + tid;
        int r = f >> 3, c = f & 7;
        if (row0 + r < N + 1)   // row N written as zeros (diss=0) -> gather sentinel
            ((uint4*)&h1b[(size_t)(row0 + r) * HID])[c] = *(const uint4*)&xs[r][c * 8];
    }
}

// ---------- fused layer-1 agg + ReLU + W2 GEMM ----------
// 2 nodes/wave (half-wave each: 4 slots x 8 dim-lanes); padded CSR rows (4-aligned):
// 2 int4 index loads + 2 vector sentinel-selects + 8 independent 16B gathers per lane.
__global__ __launch_bounds__(256) void agg1_fused(
        const int* __restrict__ row_ptr, const int* __restrict__ row_len,
        const int* __restrict__ csr_src,
        const unsigned short* __restrict__ h1b, const float* __restrict__ dis,
        const float* __restrict__ b1, const float* __restrict__ W2,
        unsigned short* __restrict__ h2b, int N) {
    __shared__ float W2t[NCLS][HID + 4];   // transposed, padded row stride 68
    __shared__ float ts[8][HID];
    int tid = threadIdx.x;
    int w = tid >> 6;
    int lane = tid & 63;
    int half = lane >> 5;      // node within wave
    int hl = lane & 31;        // lane within half
    int sub = hl & 7;          // dims sub*8 .. sub*8+7 (16B)
    int slot = hl >> 3;        // edge slot 0..3 (each owns 2 int4 runs)
    int n = blockIdx.x * 8 + w * 2 + half;
    int nc = (n < N) ? n : 0;  // clamp so tail lanes still load safely

    // issue row_ptr/row_len/dis + vector index loads BEFORE LDS staging
    int start = row_ptr[nc];   // 4-aligned by construction
    int plen = row_len[nc];    // multiple of 4
    float dn = dis[nc];
    const int4* ip = (const int4*)(csr_src + start);
    int4 q0 = ip[2 * slot];
    int4 q1 = ip[2 * slot + 1];

    for (int i = tid; i < HID * NCLS; i += 256) W2t[i & 15][i >> 4] = W2[i];
    __syncthreads();
    if (n >= N) return;        // after the only __syncthreads (no barrier below)

    // vector sentinel-select: plen % 4 == 0, one compare covers a whole int4
    int e0 = slot * 8;
    if (e0 >= plen)     q0 = make_int4(N, N, N, N);
    if (e0 + 4 >= plen) q1 = make_int4(N, N, N, N);
    const unsigned short* hp = h1b + sub * 8;
    uint4 v0 = *(const uint4*)(hp + (unsigned)q0.x * HID);
    uint4 v1 = *(const uint4*)(hp + (unsigned)q0.y * HID);
    uint4 v2 = *(const uint4*)(hp + (unsigned)q0.z * HID);
    uint4 v3 = *(const uint4*)(hp + (unsigned)q0.w * HID);
    uint4 v4 = *(const uint4*)(hp + (unsigned)q1.x * HID);
    uint4 v5 = *(const uint4*)(hp + (unsigned)q1.y * HID);
    uint4 v6 = *(const uint4*)(hp + (unsigned)q1.z * HID);
    uint4 v7 = *(const uint4*)(hp + (unsigned)q1.w * HID);
    f32x2 a0 = (bfpair(v0.x) + bfpair(v1.x)) + (bfpair(v2.x) + bfpair(v3.x));
    f32x2 a1 = (bfpair(v0.y) + bfpair(v1.y)) + (bfpair(v2.y) + bfpair(v3.y));
    f32x2 a2 = (bfpair(v0.z) + bfpair(v1.z)) + (bfpair(v2.z) + bfpair(v3.z));
    f32x2 a3 = (bfpair(v0.w) + bfpair(v1.w)) + (bfpair(v2.w) + bfpair(v3.w));
    a0 += (bfpair(v4.x) + bfpair(v5.x)) + (bfpair(v6.x) + bfpair(v7.x));
    a1 += (bfpair(v4.y) + bfpair(v5.y)) + (bfpair(v6.y) + bfpair(v7.y));
    a2 += (bfpair(v4.z) + bfpair(v5.z)) + (bfpair(v6.z) + bfpair(v7.z));
    a3 += (bfpair(v4.w) + bfpair(v5.w)) + (bfpair(v6.w) + bfpair(v7.w));
    // residual for rare rows with plen > 32 (sentinel entries included, harmless)
    for (int i = 32 + slot; i < plen; i += 4) {
        int s = csr_src[start + i];
        uint4 v = *(const uint4*)(hp + (unsigned)s * HID);
        a0 += bfpair(v.x);
        a1 += bfpair(v.y);
        a2 += bfpair(v.z);
        a3 += bfpair(v.w);
    }
    // reduce across the 4 slots (lane bits 3,4 — stays within the half)
    #pragma unroll
    for (int m = 8; m <= 16; m <<= 1) {
        a0.x += __shfl_xor(a0.x, m, 64); a0.y += __shfl_xor(a0.y, m, 64);
        a1.x += __shfl_xor(a1.x, m, 64); a1.y += __shfl_xor(a1.y, m, 64);
        a2.x += __shfl_xor(a2.x, m, 64); a2.y += __shfl_xor(a2.y, m, 64);
        a3.x += __shfl_xor(a3.x, m, 64); a3.y += __shfl_xor(a3.y, m, 64);
    }
    if (slot == 0) {
        float4 bl = ((const float4*)b1)[sub * 2];
        float4 bh = ((const float4*)b1)[sub * 2 + 1];
        float4 r0, r1;
        r0.x = fmaxf(fmaf(dn, a0.x, bl.x), 0.f);
        r0.y = fmaxf(fmaf(dn, a0.y, bl.y), 0.f);
        r0.z = fmaxf(fmaf(dn, a1.x, bl.z), 0.f);
        r0.w = fmaxf(fmaf(dn, a1.y, bl.w), 0.f);
        r1.x = fmaxf(fmaf(dn, a2.x, bh.x), 0.f);
        r1.y = fmaxf(fmaf(dn, a2.y, bh.y), 0.f);
        r1.z = fmaxf(fmaf(dn, a3.x, bh.z), 0.f);
        r1.w = fmaxf(fmaf(dn, a3.y, bh.w), 0.f);
        *(float4*)&ts[w * 2 + half][sub * 8] = r0;
        *(float4*)&ts[w * 2 + half][sub * 8 + 4] = r1;
    }
    // wave-local LDS round-trip (same wave writes+reads; compiler inserts lgkmcnt)
    int q = hl >> 4, c = hl & 15;       // q: K-half 0/1, c: output class
    const float* tp = &ts[w * 2 + half][q * 32];
    const float* wp = &W2t[c][q * 32];
    float4 t0 = *(const float4*)tp,        t1 = *(const float4*)(tp + 4);
    float4 t2 = *(const float4*)(tp + 8),  t3 = *(const float4*)(tp + 12);
    float4 t4 = *(const float4*)(tp + 16), t5 = *(const float4*)(tp + 20);
    float4 t6 = *(const float4*)(tp + 24), t7 = *(const float4*)(tp + 28);
    float4 u0 = *(const float4*)wp,        u1 = *(const float4*)(wp + 4);
    float4 u2 = *(const float4*)(wp + 8),  u3 = *(const float4*)(wp + 12);
    float4 u4 = *(const float4*)(wp + 16), u5 = *(const float4*)(wp + 20);
    float4 u6 = *(const float4*)(wp + 24), u7 = *(const float4*)(wp + 28);
    float p = t0.x * u0.x + t0.y * u0.y + t0.z * u0.z + t0.w * u0.w
            + t1.x * u1.x + t1.y * u1.y + t1.z * u1.z + t1.w * u1.w
            + t2.x * u2.x + t2.y * u2.y + t2.z * u2.z + t2.w * u2.w
            + t3.x * u3.x + t3.y * u3.y + t3.z * u3.z + t3.w * u3.w
            + t4.x * u4.x + t4.y * u4.y + t4.z * u4.z + t4.w * u4.w
            + t5.x * u5.x + t5.y * u5.y + t5.z * u5.z + t5.w * u5.w
            + t6.x * u6.x + t6.y * u6.y + t6.z * u6.z + t6.w * u6.w
            + t7.x * u7.x + t7.y * u7.y + t7.z * u7.z + t7.w * u7.w;
    p += __shfl_xor(p, 16, 64);         // combine the two K-halves
    if (hl < 16) h2b[(unsigned)n * NCLS + c] = f2bf(p * dn);
}

// ---------- fused layer-2 agg + epilogue ----------
// 8 nodes/wave (8 lanes each: 4 slots x 2 dim-lanes), padded CSR + int4 index loads
__global__ __launch_bounds__(256) void agg2_fused(
        const int* __restrict__ row_ptr, const int* __restrict__ row_len,
        const int* __restrict__ csr_src,
        const unsigned short* __restrict__ h2b, const float* __restrict__ dis,
        const float* __restrict__ b2, float* __restrict__ out, int N) {
    int t = blockIdx.x * 256 + threadIdx.x;
    int lane = t & 63;
    int grp = lane >> 3;         // node within wave (0..7)
    int gl = lane & 7;
    int slot = gl >> 1;          // edge slot 0..3
    int sub = gl & 1;            // dims sub*8 .. sub*8+7
    int n = (t >> 6) * 8 + grp;
    if (n >= N) return;          // uniform within each 8-lane group
    int start = row_ptr[n];
    int plen = row_len[n];
    const int4* ip = (const int4*)(csr_src + start);
    int4 q0 = ip[2 * slot];
    int4 q1 = ip[2 * slot + 1];
    int e0 = slot * 8;
    if (e0 >= plen)     q0 = make_int4(N, N, N, N);
    if (e0 + 4 >= plen) q1 = make_int4(N, N, N, N);
    const unsigned short* hp = h2b + sub * 8;
    uint4 v0 = *(const uint4*)(hp + (unsigned)q0.x * NCLS);
    uint4 v1 = *(const uint4*)(hp + (unsigned)q0.y * NCLS);
    uint4 v2 = *(const uint4*)(hp + (unsigned)q0.z * NCLS);
    uint4 v3 = *(const uint4*)(hp + (unsigned)q0.w * NCLS);
    uint4 v4 = *(const uint4*)(hp + (unsigned)q1.x * NCLS);
    uint4 v5 = *(const uint4*)(hp + (unsigned)q1.y * NCLS);
    uint4 v6 = *(const uint4*)(hp + (unsigned)q1.z * NCLS);
    uint4 v7 = *(const uint4*)(hp + (unsigned)q1.w * NCLS);
    f32x2 a0 = (bfpair(v0.x) + bfpair(v1.x)) + (bfpair(v2.x) + bfpair(v3.x));
    f32x2 a1 = (bfpair(v0.y) + bfpair(v1.y)) + (bfpair(v2.y) + bfpair(v3.y));
    f32x2 a2 = (bfpair(v0.z) + bfpair(v1.z)) + (bfpair(v2.z) + bfpair(v3.z));
    f32x2 a3 = (bfpair(v0.w) + bfpair(v1.w)) + (bfpair(v2.w) + bfpair(v3.w));
    a0 += (bfpair(v4.x) + bfpair(v5.x)) + (bfpair(v6.x) + bfpair(v7.x));
    a1 += (bfpair(v4.y) + bfpair(v5.y)) + (bfpair(v6.y) + bfpair(v7.y));
    a2 += (bfpair(v4.z) + bfpair(v5.z)) + (bfpair(v6.z) + bfpair(v7.z));
    a3 += (bfpair(v4.w) + bfpair(v5.w)) + (bfpair(v6.w) + bfpair(v7.w));
    for (int i = 32 + slot; i < plen; i += 4) {
        int s = csr_src[start + i];
        uint4 v = *(const uint4*)(hp + (unsigned)s * NCLS);
        a0 += bfpair(v.x);
        a1 += bfpair(v.y);
        a2 += bfpair(v.z);
        a3 += bfpair(v.w);
    }
    // reduce across 4 slots (lane bits 1,2 — stays inside the 8-lane group)
    #pragma unroll
    for (int m = 2; m <= 4; m <<= 1) {
        a0.x += __shfl_xor(a0.x, m, 64); a0.y += __shfl_xor(a0.y, m, 64);
        a1.x += __shfl_xor(a1.x, m, 64); a1.y += __shfl_xor(a1.y, m, 64);
        a2.x += __shfl_xor(a2.x, m, 64); a2.y += __shfl_xor(a2.y, m, 64);
        a3.x += __shfl_xor(a3.x, m, 64); a3.y += __shfl_xor(a3.y, m, 64);
    }
    if (slot == 0) {
        float dn = dis[n];
        float4 bl = ((const float4*)b2)[sub * 2];
        float4 bh = ((const float4*)b2)[sub * 2 + 1];
        float4 o0, o1;
        o0.x = fmaf(dn, a0.x, bl.x); o0.y = fmaf(dn, a0.y, bl.y);
        o0.z = fmaf(dn, a1.x, bl.z); o0.w = fmaf(dn, a1.y, bl.w);
        o1.x = fmaf(dn, a2.x, bh.x); o1.y = fmaf(dn, a2.y, bh.y);
        o1.z = fmaf(dn, a3.x, bh.z); o1.w = fmaf(dn, a3.y, bh.w);
        float* op = out + (unsigned)n * NCLS + sub * 8;
        *(float4*)op = o0;
        *(float4*)(op + 4) = o1;
    }
}

extern "C" void kernel_launch(void* const* d_in, const int* in_sizes, int n_in,
                              void* d_out, int out_size, void* d_ws, size_t ws_size,
                              hipStream_t stream) {
    const float* x   = (const float*)d_in[0];
    const int*   src = (const int*)  d_in[1];
    const int*   dst = (const int*)  d_in[2];
    const float* W1  = (const float*)d_in[3];
    const float* b1  = (const float*)d_in[4];
    const float* W2  = (const float*)d_in[5];
    const float* b2  = (const float*)d_in[6];
    float* out = (float*)d_out;
    int E = in_sizes[1];
    int N = in_sizes[0] / F_IN;
    int NB = (N + BNODES - 1) >> BSHIFT;
    int nchunks = (E + CHUNK - 1) / CHUNK;   // 208 for E=1.7M

    char* ws = (char*)d_ws;
    size_t off = 0;
    auto alloc = [&](size_t bytes) { size_t o = off; off = (off + bytes + 255) & ~(size_t)255; return (void*)(ws + o); };
    int*   bucket_count  = (int*)  alloc((size_t)NB * 4);
    int*   bucket_base   = (int*)  alloc((size_t)(NB + 1) * 4);
    int*   bucket_cursor = (int*)  alloc((size_t)NB * 4);
    int*   row_ptr       = (int*)  alloc((size_t)(N + 1) * 4);
    int*   row_len       = (int*)  alloc((size_t)N * 4);
    int*   csr_src       = (int*)  alloc((size_t)(E + (size_t)NB * PADB + 64) * 4);  // padded CSR
    float* dis           = (float*)alloc((size_t)N * 4);
    unsigned short* w1t  = (unsigned short*)alloc((size_t)F_IN * HID * 2);
    unsigned short* h1b  = (unsigned short*)alloc((size_t)(N + 1) * HID * 2);  // +1 sentinel row
    unsigned short* h2b  = (unsigned short*)alloc((size_t)(N + 1) * NCLS * 2); // +1 sentinel row
    // part[] aliases h1b: dead before gemm1 writes h1b (E*4 = 6.8MB <= (N+1)*HID*2 = 12.8MB)
    unsigned int* part   = (unsigned int*)h1b;

    hipMemsetAsync(bucket_count, 0, (size_t)NB * 4, stream);   // capture-legal memset node
    hist_w1t_kernel<<<nchunks + 1, 256, 0, stream>>>(dst, bucket_count, W1, w1t, h2b, E, N, NB, nchunks);
    bucket_scan    <<<1, 512, 0, stream>>>(bucket_count, bucket_base, bucket_cursor, NB, E);
    scatter_kernel <<<nchunks, 256, 0, stream>>>(src, dst, bucket_cursor, part, E, NB);
    csr_build      <<<NB, 256, 0, stream>>>(part, bucket_base, csr_src, row_ptr, row_len, dis, N);
    gemm1_kernel   <<<(N + 64) / 64, 256, 0, stream>>>(x, w1t, dis, h1b, N);  // +1 covers row N
    agg1_fused     <<<(N + 7) / 8, 256, 0, stream>>>(row_ptr, row_len, csr_src, h1b, dis, b1, W2, h2b, N);
    agg2_fused     <<<(N + 31) / 32, 256, 0, stream>>>(row_ptr, row_len, csr_src, h2b, dis, b2, out, N);
}

// Round 12
// 198.419 us; speedup vs baseline: 1.0559x; 1.0085x over previous
//
#include <hip/hip_runtime.h>

#define F_IN 128
#define HID  64
#define NCLS 16

#define BSHIFT 8            // 256 nodes per bucket
#define BNODES 256
#define NB_MAX 512          // max buckets (N<=128k)
#define CHUNK  8192         // edges per partition block
#define CAP    8192         // max edges per bucket in LDS (mean 4352, 50+ sigma margin)
#define PADB   772          // per-bucket padding slack: 256 rows * 3 + 4 (base align)

typedef __attribute__((ext_vector_type(2))) float f32x2;
typedef __attribute__((ext_vector_type(8))) short bf16x8;
typedef __attribute__((ext_vector_type(4))) float f32x4;

// round-to-nearest-even fp32 -> bf16
__device__ __forceinline__ unsigned short f2bf(float f) {
    unsigned int u = __float_as_uint(f);
    u += 0x7FFFu + ((u >> 16) & 1u);
    return (unsigned short)(u >> 16);
}
// one dword = 2 packed bf16 -> f32x2 (2 VALU unpack + packed add)
// NOTE: do NOT replace with __builtin_amdgcn_fdot2_f32_bf16 — it compiles on
// gfx950 but produces wrong numerics (round-9 failure, absmax 0.57).
__device__ __forceinline__ f32x2 bfpair(unsigned int u) {
    f32x2 r;
    r.x = __uint_as_float(u << 16);
    r.y = __uint_as_float(u & 0xFFFF0000u);
    return r;
}

// ---------- pass 1: per-block LDS bucket histogram -> blk_cnt row + global bucket_count ----------
// bucket_count zeroed by hipMemsetAsync before this launch.
__global__ __launch_bounds__(256) void hist_w1t_kernel(const int* __restrict__ dst,
                                                       int* __restrict__ bucket_count,
                                                       int* __restrict__ blk_cnt,
                                                       const float* __restrict__ W1,
                                                       unsigned short* __restrict__ w1t,
                                                       unsigned short* __restrict__ h2b,
                                                       int E, int N, int NB, int nchunks) {
    int blk = blockIdx.x;
    int tid = threadIdx.x;
    if (blk == nchunks) {           // fused W1 -> bf16 transpose block
        for (int i = tid; i < F_IN * HID; i += 256) {
            int k = i >> 6, n = i & 63;
            w1t[n * F_IN + k] = f2bf(W1[i]);
        }
        if (tid < NCLS) h2b[(size_t)N * NCLS + tid] = 0;   // zero sentinel row for agg2
        return;
    }
    __shared__ int hist[NB_MAX];
    for (int i = tid; i < NB; i += 256) hist[i] = 0;
    __syncthreads();
    int cb = blk * CHUNK;
    #pragma unroll
    for (int k = 0; k < CHUNK / 1024; k++) {
        int e = cb + (k * 256 + tid) * 4;
        if (e + 3 < E) {
            int4 d4 = *(const int4*)&dst[e];
            atomicAdd(&hist[d4.x >> BSHIFT], 1);
            atomicAdd(&hist[d4.y >> BSHIFT], 1);
            atomicAdd(&hist[d4.z >> BSHIFT], 1);
            atomicAdd(&hist[d4.w >> BSHIFT], 1);
        } else {
            for (int t = 0; t < 4; t++)
                if (e + t < E) atomicAdd(&hist[dst[e + t] >> BSHIFT], 1);
        }
    }
    __syncthreads();
    for (int i = tid; i < NB; i += 256) {
        int c = hist[i];
        blk_cnt[(size_t)blk * NB + i] = c;       // per-block counts for scatter reuse
        if (c) atomicAdd(&bucket_count[i], c);   // 391 addrs x 208 blocks: cheap
    }
}

// ---------- pass 2: tiny single-block scan of bucket totals -> bases + cursors ----------
__global__ __launch_bounds__(512) void bucket_scan(const int* __restrict__ bucket_count,
                                                   int* __restrict__ bucket_base,
                                                   int* __restrict__ bucket_cursor,
                                                   int NB, int E) {
    __shared__ int s[512];
    int tid = threadIdx.x;
    int v = (tid < NB) ? bucket_count[tid] : 0;
    s[tid] = v;
    __syncthreads();
    for (int off = 1; off < 512; off <<= 1) {
        int t = (tid >= off) ? s[tid - off] : 0;
        __syncthreads();
        s[tid] += t;
        __syncthreads();
    }
    if (tid < NB) {
        int base = s[tid] - v;
        bucket_base[tid] = base;
        bucket_cursor[tid] = base;
    }
    if (tid == 0) bucket_base[NB] = E;
}

// ---------- pass 3: partition using precomputed per-block counts (no re-count pass) ----------
// Within-bucket order is arrival order (nondeterministic) — csr_build sorts by node anyway.
__global__ __launch_bounds__(256) void scatter_kernel(const int* __restrict__ src,
                                                      const int* __restrict__ dst,
                                                      const int* __restrict__ blk_cnt,
                                                      int* __restrict__ bucket_cursor,
                                                      unsigned int* __restrict__ part,
                                                      int E, int NB) {
    __shared__ int cur[NB_MAX];
    int tid = threadIdx.x;
    int blk = blockIdx.x;
    for (int i = tid; i < NB; i += 256) {       // reserve contiguous ranges from own counts
        int c = blk_cnt[(size_t)blk * NB + i];
        cur[i] = c ? atomicAdd(&bucket_cursor[i], c) : 0;
    }
    __syncthreads();
    int cb = blk * CHUNK;
    #pragma unroll
    for (int k = 0; k < CHUNK / 1024; k++) {   // scatter into reserved ranges
        int e = cb + (k * 256 + tid) * 4;
        if (e + 3 < E) {
            int4 d4 = *(const int4*)&dst[e];
            int4 s4 = *(const int4*)&src[e];
            int p0 = atomicAdd(&cur[d4.x >> BSHIFT], 1);
            part[p0] = ((unsigned int)(d4.x & (BNODES - 1)) << 24) | (unsigned int)s4.x;
            int p1 = atomicAdd(&cur[d4.y >> BSHIFT], 1);
            part[p1] = ((unsigned int)(d4.y & (BNODES - 1)) << 24) | (unsigned int)s4.y;
            int p2 = atomicAdd(&cur[d4.z >> BSHIFT], 1);
            part[p2] = ((unsigned int)(d4.z & (BNODES - 1)) << 24) | (unsigned int)s4.z;
            int p3 = atomicAdd(&cur[d4.w >> BSHIFT], 1);
            part[p3] = ((unsigned int)(d4.w & (BNODES - 1)) << 24) | (unsigned int)s4.w;
        } else {
            for (int t = 0; t < 4; t++)
                if (e + t < E) {
                    int d = dst[e + t];
                    int pos = atomicAdd(&cur[d >> BSHIFT], 1);
                    part[pos] = ((unsigned int)(d & (BNODES - 1)) << 24) | (unsigned int)src[e + t];
                }
        }
    }
}

// ---------- pass 4: per-bucket counting sort -> PADDED csr (rows 4-aligned, sentinel N) ----------
__global__ __launch_bounds__(256) void csr_build(const unsigned int* __restrict__ part,
                                                 const int* __restrict__ bucket_base,
                                                 int* __restrict__ csr_src,
                                                 int* __restrict__ row_ptr,
                                                 int* __restrict__ row_len,
                                                 float* __restrict__ dis,
                                                 int N) {
    __shared__ unsigned int eL[CAP];
    __shared__ unsigned int outL[CAP + PADB];
    __shared__ int cnt[BNODES];
    __shared__ int sc[BNODES];
    __shared__ int cur[BNODES];
    int tid = threadIdx.x;
    int b = blockIdx.x;
    int eB = bucket_base[b];
    int eN = bucket_base[b + 1] - eB;
    if (eN > CAP) eN = CAP;
    int pb = (eB + b * PADB + 3) & ~3;   // 4-aligned padded bucket base

    cnt[tid] = 0;
    __syncthreads();
    for (int i = tid; i < eN; i += 256) {
        unsigned int v = part[eB + i];
        eL[i] = v;
        atomicAdd(&cnt[v >> 24], 1);
    }
    // sentinel-init the padded output region (real edges overwrite below)
    for (int i = tid; i < eN + PADB; i += 256) outL[i] = (unsigned int)N;
    __syncthreads();
    int myc = cnt[tid];
    int pd = (myc + 3) & ~3;        // padded row length (multiple of 4)
    sc[tid] = pd;
    __syncthreads();
    for (int off = 1; off < 256; off <<= 1) {
        int t = (tid >= off) ? sc[tid - off] : 0;
        __syncthreads();
        sc[tid] += t;
        __syncthreads();
    }
    int excl = sc[tid] - pd;        // multiple of 4
    cur[tid] = excl;
    int gnode = b * BNODES + tid;
    if (gnode < N) {
        row_ptr[gnode] = pb + excl;  // 4-aligned: pb aligned + excl mult of 4
        row_len[gnode] = pd;
        float d = (float)myc;
        dis[gnode] = d > 0.0f ? rsqrtf(fmaxf(d, 1.0f)) : 0.0f;
    }
    __syncthreads();
    int pTot = sc[BNODES - 1];      // padded bucket total (<= eN + PADB)
    for (int i = tid; i < eN; i += 256) {
        unsigned int v = eL[i];
        int pos = atomicAdd(&cur[v >> 24], 1);
        outL[pos] = v & 0xFFFFFFu;
    }
    __syncthreads();
    for (int i = tid; i < pTot; i += 256)
        csr_src[pb + i] = (int)outL[i];
}

// ---------- gemm1 via MFMA bf16: 64 rows/block; also emits zeroed sentinel row N ----------
__global__ __launch_bounds__(256) void gemm1_kernel(
        const float* __restrict__ x, const unsigned short* __restrict__ w1t,
        const float* __restrict__ dis, unsigned short* __restrict__ h1b, int N) {
    __shared__ unsigned short xs[64][136];
    __shared__ unsigned short wsb[64][136];
    __shared__ float diss[64];
    int tid = threadIdx.x;
    int w = tid >> 6;
    int lane = tid & 63;
    int row0 = blockIdx.x * 64;

    #pragma unroll
    for (int it = 0; it < 8; it++) {
        int f = it * 256 + tid;
        int r = f >> 5, c = f & 31;
        float4 v = make_float4(0.f, 0.f, 0.f, 0.f);
        if (row0 + r < N) v = ((const float4*)x)[(size_t)(row0 + r) * 32 + c];
        unsigned int p0 = (unsigned int)f2bf(v.x) | ((unsigned int)f2bf(v.y) << 16);
        unsigned int p1 = (unsigned int)f2bf(v.z) | ((unsigned int)f2bf(v.w) << 16);
        *(uint2*)&xs[r][c * 4] = make_uint2(p0, p1);
    }
    #pragma unroll
    for (int it = 0; it < 4; it++) {
        int f = it * 256 + tid;
        int r = f >> 4, c = f & 15;
        *(uint4*)&wsb[r][c * 8] = ((const uint4*)w1t)[f];
    }
    if (tid < 64) diss[tid] = (row0 + tid < N) ? dis[row0 + tid] : 0.f;
    __syncthreads();

    int q = lane >> 4;
    int l15 = lane & 15;
    f32x4 acc[4] = {{0,0,0,0},{0,0,0,0},{0,0,0,0},{0,0,0,0}};
    bf16x8 a[4];
    #pragma unroll
    for (int kk = 0; kk < 4; kk++)
        a[kk] = *(const bf16x8*)&xs[w * 16 + l15][kk * 32 + q * 8];
    #pragma unroll
    for (int kk = 0; kk < 4; kk++) {
        #pragma unroll
        for (int ct = 0; ct < 4; ct++) {
            bf16x8 b = *(const bf16x8*)&wsb[ct * 16 + l15][kk * 32 + q * 8];
            acc[ct] = __builtin_amdgcn_mfma_f32_16x16x32_bf16(a[kk], b, acc[ct], 0, 0, 0);
        }
    }
    __syncthreads();
    #pragma unroll
    for (int ct = 0; ct < 4; ct++) {
        #pragma unroll
        for (int r = 0; r < 4; r++) {
            int m = w * 16 + q * 4 + r;
            xs[m][ct * 16 + l15] = f2bf(acc[ct][r] * diss[m]);
        }
    }
    __syncthreads();
    #pragma unroll
    for (int it = 0; it < 2; it++) {
        int f = it * 256 + tid;
        int r = f >> 3, c = f & 7;
        if (row0 + r < N + 1)   // row N written as zeros (diss=0) -> gather sentinel
            ((uint4*)&h1b[(size_t)(row0 + r) * HID])[c] = *(const uint4*)&xs[r][c * 8];
    }
}

// ---------- fused layer-1 agg + ReLU + W2 GEMM ----------
// 2 nodes/wave (half-wave each: 4 slots x 8 dim-lanes); padded CSR rows (4-aligned):
// 2 int4 index loads + 2 vector sentinel-selects + 8 independent 16B gathers per lane.
__global__ __launch_bounds__(256) void agg1_fused(
        const int* __restrict__ row_ptr, const int* __restrict__ row_len,
        const int* __restrict__ csr_src,
        const unsigned short* __restrict__ h1b, const float* __restrict__ dis,
        const float* __restrict__ b1, const float* __restrict__ W2,
        unsigned short* __restrict__ h2b, int N) {
    __shared__ float W2t[NCLS][HID + 4];   // transposed, padded row stride 68
    __shared__ float ts[8][HID];
    int tid = threadIdx.x;
    int w = tid >> 6;
    int lane = tid & 63;
    int half = lane >> 5;      // node within wave
    int hl = lane & 31;        // lane within half
    int sub = hl & 7;          // dims sub*8 .. sub*8+7 (16B)
    int slot = hl >> 3;        // edge slot 0..3 (each owns 2 int4 runs)
    int n = blockIdx.x * 8 + w * 2 + half;
    int nc = (n < N) ? n : 0;  // clamp so tail lanes still load safely

    // issue row_ptr/row_len/dis + vector index loads BEFORE LDS staging
    int start = row_ptr[nc];   // 4-aligned by construction
    int plen = row_len[nc];    // multiple of 4
    float dn = dis[nc];
    const int4* ip = (const int4*)(csr_src + start);
    int4 q0 = ip[2 * slot];
    int4 q1 = ip[2 * slot + 1];

    for (int i = tid; i < HID * NCLS; i += 256) W2t[i & 15][i >> 4] = W2[i];
    __syncthreads();
    if (n >= N) return;        // after the only __syncthreads (no barrier below)

    // vector sentinel-select: plen % 4 == 0, one compare covers a whole int4
    int e0 = slot * 8;
    if (e0 >= plen)     q0 = make_int4(N, N, N, N);
    if (e0 + 4 >= plen) q1 = make_int4(N, N, N, N);
    const unsigned short* hp = h1b + sub * 8;
    uint4 v0 = *(const uint4*)(hp + (unsigned)q0.x * HID);
    uint4 v1 = *(const uint4*)(hp + (unsigned)q0.y * HID);
    uint4 v2 = *(const uint4*)(hp + (unsigned)q0.z * HID);
    uint4 v3 = *(const uint4*)(hp + (unsigned)q0.w * HID);
    uint4 v4 = *(const uint4*)(hp + (unsigned)q1.x * HID);
    uint4 v5 = *(const uint4*)(hp + (unsigned)q1.y * HID);
    uint4 v6 = *(const uint4*)(hp + (unsigned)q1.z * HID);
    uint4 v7 = *(const uint4*)(hp + (unsigned)q1.w * HID);
    f32x2 a0 = (bfpair(v0.x) + bfpair(v1.x)) + (bfpair(v2.x) + bfpair(v3.x));
    f32x2 a1 = (bfpair(v0.y) + bfpair(v1.y)) + (bfpair(v2.y) + bfpair(v3.y));
    f32x2 a2 = (bfpair(v0.z) + bfpair(v1.z)) + (bfpair(v2.z) + bfpair(v3.z));
    f32x2 a3 = (bfpair(v0.w) + bfpair(v1.w)) + (bfpair(v2.w) + bfpair(v3.w));
    a0 += (bfpair(v4.x) + bfpair(v5.x)) + (bfpair(v6.x) + bfpair(v7.x));
    a1 += (bfpair(v4.y) + bfpair(v5.y)) + (bfpair(v6.y) + bfpair(v7.y));
    a2 += (bfpair(v4.z) + bfpair(v5.z)) + (bfpair(v6.z) + bfpair(v7.z));
    a3 += (bfpair(v4.w) + bfpair(v5.w)) + (bfpair(v6.w) + bfpair(v7.w));
    // residual for rare rows with plen > 32 (sentinel entries included, harmless)
    for (int i = 32 + slot; i < plen; i += 4) {
        int s = csr_src[start + i];
        uint4 v = *(const uint4*)(hp + (unsigned)s * HID);
        a0 += bfpair(v.x);
        a1 += bfpair(v.y);
        a2 += bfpair(v.z);
        a3 += bfpair(v.w);
    }
    // reduce across the 4 slots (lane bits 3,4 — stays within the half)
    #pragma unroll
    for (int m = 8; m <= 16; m <<= 1) {
        a0.x += __shfl_xor(a0.x, m, 64); a0.y += __shfl_xor(a0.y, m, 64);
        a1.x += __shfl_xor(a1.x, m, 64); a1.y += __shfl_xor(a1.y, m, 64);
        a2.x += __shfl_xor(a2.x, m, 64); a2.y += __shfl_xor(a2.y, m, 64);
        a3.x += __shfl_xor(a3.x, m, 64); a3.y += __shfl_xor(a3.y, m, 64);
    }
    if (slot == 0) {
        float4 bl = ((const float4*)b1)[sub * 2];
        float4 bh = ((const float4*)b1)[sub * 2 + 1];
        float4 r0, r1;
        r0.x = fmaxf(fmaf(dn, a0.x, bl.x), 0.f);
        r0.y = fmaxf(fmaf(dn, a0.y, bl.y), 0.f);
        r0.z = fmaxf(fmaf(dn, a1.x, bl.z), 0.f);
        r0.w = fmaxf(fmaf(dn, a1.y, bl.w), 0.f);
        r1.x = fmaxf(fmaf(dn, a2.x, bh.x), 0.f);
        r1.y = fmaxf(fmaf(dn, a2.y, bh.y), 0.f);
        r1.z = fmaxf(fmaf(dn, a3.x, bh.z), 0.f);
        r1.w = fmaxf(fmaf(dn, a3.y, bh.w), 0.f);
        *(float4*)&ts[w * 2 + half][sub * 8] = r0;
        *(float4*)&ts[w * 2 + half][sub * 8 + 4] = r1;
    }
    // wave-local LDS round-trip (same wave writes+reads; compiler inserts lgkmcnt)
    int q = hl >> 4, c = hl & 15;       // q: K-half 0/1, c: output class
    const float* tp = &ts[w * 2 + half][q * 32];
    const float* wp = &W2t[c][q * 32];
    float4 t0 = *(const float4*)tp,        t1 = *(const float4*)(tp + 4);
    float4 t2 = *(const float4*)(tp + 8),  t3 = *(const float4*)(tp + 12);
    float4 t4 = *(const float4*)(tp + 16), t5 = *(const float4*)(tp + 20);
    float4 t6 = *(const float4*)(tp + 24), t7 = *(const float4*)(tp + 28);
    float4 u0 = *(const float4*)wp,        u1 = *(const float4*)(wp + 4);
    float4 u2 = *(const float4*)(wp + 8),  u3 = *(const float4*)(wp + 12);
    float4 u4 = *(const float4*)(wp + 16), u5 = *(const float4*)(wp + 20);
    float4 u6 = *(const float4*)(wp + 24), u7 = *(const float4*)(wp + 28);
    float p = t0.x * u0.x + t0.y * u0.y + t0.z * u0.z + t0.w * u0.w
            + t1.x * u1.x + t1.y * u1.y + t1.z * u1.z + t1.w * u1.w
            + t2.x * u2.x + t2.y * u2.y + t2.z * u2.z + t2.w * u2.w
            + t3.x * u3.x + t3.y * u3.y + t3.z * u3.z + t3.w * u3.w
            + t4.x * u4.x + t4.y * u4.y + t4.z * u4.z + t4.w * u4.w
            + t5.x * u5.x + t5.y * u5.y + t5.z * u5.z + t5.w * u5.w
            + t6.x * u6.x + t6.y * u6.y + t6.z * u6.z + t6.w * u6.w
            + t7.x * u7.x + t7.y * u7.y + t7.z * u7.z + t7.w * u7.w;
    p += __shfl_xor(p, 16, 64);         // combine the two K-halves
    if (hl < 16) h2b[(unsigned)n * NCLS + c] = f2bf(p * dn);
}

// ---------- fused layer-2 agg + epilogue ----------
// 8 nodes/wave (8 lanes each: 4 slots x 2 dim-lanes), padded CSR + int4 index loads
__global__ __launch_bounds__(256) void agg2_fused(
        const int* __restrict__ row_ptr, const int* __restrict__ row_len,
        const int* __restrict__ csr_src,
        const unsigned short* __restrict__ h2b, const float* __restrict__ dis,
        const float* __restrict__ b2, float* __restrict__ out, int N) {
    int t = blockIdx.x * 256 + threadIdx.x;
    int lane = t & 63;
    int grp = lane >> 3;         // node within wave (0..7)
    int gl = lane & 7;
    int slot = gl >> 1;          // edge slot 0..3
    int sub = gl & 1;            // dims sub*8 .. sub*8+7
    int n = (t >> 6) * 8 + grp;
    if (n >= N) return;          // uniform within each 8-lane group
    int start = row_ptr[n];
    int plen = row_len[n];
    const int4* ip = (const int4*)(csr_src + start);
    int4 q0 = ip[2 * slot];
    int4 q1 = ip[2 * slot + 1];
    int e0 = slot * 8;
    if (e0 >= plen)     q0 = make_int4(N, N, N, N);
    if (e0 + 4 >= plen) q1 = make_int4(N, N, N, N);
    const unsigned short* hp = h2b + sub * 8;
    uint4 v0 = *(const uint4*)(hp + (unsigned)q0.x * NCLS);
    uint4 v1 = *(const uint4*)(hp + (unsigned)q0.y * NCLS);
    uint4 v2 = *(const uint4*)(hp + (unsigned)q0.z * NCLS);
    uint4 v3 = *(const uint4*)(hp + (unsigned)q0.w * NCLS);
    uint4 v4 = *(const uint4*)(hp + (unsigned)q1.x * NCLS);
    uint4 v5 = *(const uint4*)(hp + (unsigned)q1.y * NCLS);
    uint4 v6 = *(const uint4*)(hp + (unsigned)q1.z * NCLS);
    uint4 v7 = *(const uint4*)(hp + (unsigned)q1.w * NCLS);
    f32x2 a0 = (bfpair(v0.x) + bfpair(v1.x)) + (bfpair(v2.x) + bfpair(v3.x));
    f32x2 a1 = (bfpair(v0.y) + bfpair(v1.y)) + (bfpair(v2.y) + bfpair(v3.y));
    f32x2 a2 = (bfpair(v0.z) + bfpair(v1.z)) + (bfpair(v2.z) + bfpair(v3.z));
    f32x2 a3 = (bfpair(v0.w) + bfpair(v1.w)) + (bfpair(v2.w) + bfpair(v3.w));
    a0 += (bfpair(v4.x) + bfpair(v5.x)) + (bfpair(v6.x) + bfpair(v7.x));
    a1 += (bfpair(v4.y) + bfpair(v5.y)) + (bfpair(v6.y) + bfpair(v7.y));
    a2 += (bfpair(v4.z) + bfpair(v5.z)) + (bfpair(v6.z) + bfpair(v7.z));
    a3 += (bfpair(v4.w) + bfpair(v5.w)) + (bfpair(v6.w) + bfpair(v7.w));
    for (int i = 32 + slot; i < plen; i += 4) {
        int s = csr_src[start + i];
        uint4 v = *(const uint4*)(hp + (unsigned)s * NCLS);
        a0 += bfpair(v.x);
        a1 += bfpair(v.y);
        a2 += bfpair(v.z);
        a3 += bfpair(v.w);
    }
    // reduce across 4 slots (lane bits 1,2 — stays inside the 8-lane group)
    #pragma unroll
    for (int m = 2; m <= 4; m <<= 1) {
        a0.x += __shfl_xor(a0.x, m, 64); a0.y += __shfl_xor(a0.y, m, 64);
        a1.x += __shfl_xor(a1.x, m, 64); a1.y += __shfl_xor(a1.y, m, 64);
        a2.x += __shfl_xor(a2.x, m, 64); a2.y += __shfl_xor(a2.y, m, 64);
        a3.x += __shfl_xor(a3.x, m, 64); a3.y += __shfl_xor(a3.y, m, 64);
    }
    if (slot == 0) {
        float dn = dis[n];
        float4 bl = ((const float4*)b2)[sub * 2];
        float4 bh = ((const float4*)b2)[sub * 2 + 1];
        float4 o0, o1;
        o0.x = fmaf(dn, a0.x, bl.x); o0.y = fmaf(dn, a0.y, bl.y);
        o0.z = fmaf(dn, a1.x, bl.z); o0.w = fmaf(dn, a1.y, bl.w);
        o1.x = fmaf(dn, a2.x, bh.x); o1.y = fmaf(dn, a2.y, bh.y);
        o1.z = fmaf(dn, a3.x, bh.z); o1.w = fmaf(dn, a3.y, bh.w);
        float* op = out + (unsigned)n * NCLS + sub * 8;
        *(float4*)op = o0;
        *(float4*)(op + 4) = o1;
    }
}

extern "C" void kernel_launch(void* const* d_in, const int* in_sizes, int n_in,
                              void* d_out, int out_size, void* d_ws, size_t ws_size,
                              hipStream_t stream) {
    const float* x   = (const float*)d_in[0];
    const int*   src = (const int*)  d_in[1];
    const int*   dst = (const int*)  d_in[2];
    const float* W1  = (const float*)d_in[3];
    const float* b1  = (const float*)d_in[4];
    const float* W2  = (const float*)d_in[5];
    const float* b2  = (const float*)d_in[6];
    float* out = (float*)d_out;
    int E = in_sizes[1];
    int N = in_sizes[0] / F_IN;
    int NB = (N + BNODES - 1) >> BSHIFT;
    int nchunks = (E + CHUNK - 1) / CHUNK;   // 208 for E=1.7M

    char* ws = (char*)d_ws;
    size_t off = 0;
    auto alloc = [&](size_t bytes) { size_t o = off; off = (off + bytes + 255) & ~(size_t)255; return (void*)(ws + o); };
    int*   bucket_count  = (int*)  alloc((size_t)NB * 4);
    int*   bucket_base   = (int*)  alloc((size_t)(NB + 1) * 4);
    int*   bucket_cursor = (int*)  alloc((size_t)NB * 4);
    int*   blk_cnt       = (int*)  alloc((size_t)nchunks * NB * 4);
    int*   row_ptr       = (int*)  alloc((size_t)(N + 1) * 4);
    int*   row_len       = (int*)  alloc((size_t)N * 4);
    int*   csr_src       = (int*)  alloc((size_t)(E + (size_t)NB * PADB + 64) * 4);  // padded CSR
    float* dis           = (float*)alloc((size_t)N * 4);
    unsigned short* w1t  = (unsigned short*)alloc((size_t)F_IN * HID * 2);
    unsigned short* h1b  = (unsigned short*)alloc((size_t)(N + 1) * HID * 2);  // +1 sentinel row
    unsigned short* h2b  = (unsigned short*)alloc((size_t)(N + 1) * NCLS * 2); // +1 sentinel row
    // part[] aliases h1b: dead before gemm1 writes h1b (E*4 = 6.8MB <= (N+1)*HID*2 = 12.8MB)
    unsigned int* part   = (unsigned int*)h1b;

    hipMemsetAsync(bucket_count, 0, (size_t)NB * 4, stream);   // capture-legal memset node
    hist_w1t_kernel<<<nchunks + 1, 256, 0, stream>>>(dst, bucket_count, blk_cnt, W1, w1t, h2b, E, N, NB, nchunks);
    bucket_scan    <<<1, 512, 0, stream>>>(bucket_count, bucket_base, bucket_cursor, NB, E);
    scatter_kernel <<<nchunks, 256, 0, stream>>>(src, dst, blk_cnt, bucket_cursor, part, E, NB);
    csr_build      <<<NB, 256, 0, stream>>>(part, bucket_base, csr_src, row_ptr, row_len, dis, N);
    gemm1_kernel   <<<(N + 64) / 64, 256, 0, stream>>>(x, w1t, dis, h1b, N);  // +1 covers row N
    agg1_fused     <<<(N + 7) / 8, 256, 0, stream>>>(row_ptr, row_len, csr_src, h1b, dis, b1, W2, h2b, N);
    agg2_fused     <<<(N + 31) / 32, 256, 0, stream>>>(row_ptr, row_len, csr_src, h2b, dis, b2, out, N);
}

// Round 13
// 197.158 us; speedup vs baseline: 1.0626x; 1.0064x over previous
//
#include <hip/hip_runtime.h>

#define F_IN 128
#define HID  64
#define NCLS 16

#define BSHIFT 8            // 256 nodes per bucket
#define BNODES 256
#define NB_MAX 512          // max buckets (N<=128k)
#define CHUNK  8192         // edges per partition block
#define CAP    8192         // fixed part[] slot per bucket (mean 4352, 50+ sigma margin)
#define PADB   772          // csr per-bucket padding slack: 256 rows * 3 + align
#define CAPP   (CAP + PADB) // fixed csr slot per bucket (8964, multiple of 4)

typedef __attribute__((ext_vector_type(2))) float f32x2;
typedef __attribute__((ext_vector_type(8))) short bf16x8;
typedef __attribute__((ext_vector_type(4))) float f32x4;

// round-to-nearest-even fp32 -> bf16
__device__ __forceinline__ unsigned short f2bf(float f) {
    unsigned int u = __float_as_uint(f);
    u += 0x7FFFu + ((u >> 16) & 1u);
    return (unsigned short)(u >> 16);
}
// one dword = 2 packed bf16 -> f32x2 (2 VALU unpack + packed add)
// NOTE: do NOT replace with __builtin_amdgcn_fdot2_f32_bf16 — it compiles on
// gfx950 but produces wrong numerics (round-9 failure, absmax 0.57).
__device__ __forceinline__ f32x2 bfpair(unsigned int u) {
    f32x2 r;
    r.x = __uint_as_float(u << 16);
    r.y = __uint_as_float(u & 0xFFFF0000u);
    return r;
}

// ---------- tiny kernel: W1 -> bf16 transpose + h2b sentinel row ----------
__global__ __launch_bounds__(256) void w1t_kernel(const float* __restrict__ W1,
                                                  unsigned short* __restrict__ w1t,
                                                  unsigned short* __restrict__ h2b, int N) {
    int tid = threadIdx.x;
    for (int i = tid; i < F_IN * HID; i += 256) {
        int k = i >> 6, n = i & 63;
        w1t[n * F_IN + k] = f2bf(W1[i]);
    }
    if (tid < NCLS) h2b[(size_t)N * NCLS + tid] = 0;   // zero sentinel row for agg2
}

// ---------- pass 1: self-reserving partition into FIXED-capacity buckets ----------
// part[b*CAP + ofs]; bucket_cursor zeroed by hipMemsetAsync. Within-bucket order is
// arrival order (nondeterministic) — csr_build counting-sorts by node anyway.
__global__ __launch_bounds__(256) void scatter_kernel(const int* __restrict__ src,
                                                      const int* __restrict__ dst,
                                                      int* __restrict__ bucket_cursor,
                                                      unsigned int* __restrict__ part,
                                                      int E, int NB) {
    __shared__ int cnt[NB_MAX];
    __shared__ int cur[NB_MAX];
    int tid = threadIdx.x;
    int blk = blockIdx.x;
    for (int i = tid; i < NB; i += 256) cnt[i] = 0;
    __syncthreads();
    int cb = blk * CHUNK;
    #pragma unroll
    for (int k = 0; k < CHUNK / 1024; k++) {   // pass A: count own chunk
        int e = cb + (k * 256 + tid) * 4;
        if (e + 3 < E) {
            int4 d4 = *(const int4*)&dst[e];
            atomicAdd(&cnt[d4.x >> BSHIFT], 1);
            atomicAdd(&cnt[d4.y >> BSHIFT], 1);
            atomicAdd(&cnt[d4.z >> BSHIFT], 1);
            atomicAdd(&cnt[d4.w >> BSHIFT], 1);
        } else {
            for (int t = 0; t < 4; t++)
                if (e + t < E) atomicAdd(&cnt[dst[e + t] >> BSHIFT], 1);
        }
    }
    __syncthreads();
    for (int i = tid; i < NB; i += 256) {       // reserve ranges in fixed slots
        int c = cnt[i];
        cur[i] = i * CAP + (c ? atomicAdd(&bucket_cursor[i], c) : 0);
    }
    __syncthreads();
    #pragma unroll
    for (int k = 0; k < CHUNK / 1024; k++) {   // pass B: scatter (dst re-read L2-hot)
        int e = cb + (k * 256 + tid) * 4;
        if (e + 3 < E) {
            int4 d4 = *(const int4*)&dst[e];
            int4 s4 = *(const int4*)&src[e];
            int p0 = atomicAdd(&cur[d4.x >> BSHIFT], 1);
            part[p0] = ((unsigned int)(d4.x & (BNODES - 1)) << 24) | (unsigned int)s4.x;
            int p1 = atomicAdd(&cur[d4.y >> BSHIFT], 1);
            part[p1] = ((unsigned int)(d4.y & (BNODES - 1)) << 24) | (unsigned int)s4.y;
            int p2 = atomicAdd(&cur[d4.z >> BSHIFT], 1);
            part[p2] = ((unsigned int)(d4.z & (BNODES - 1)) << 24) | (unsigned int)s4.z;
            int p3 = atomicAdd(&cur[d4.w >> BSHIFT], 1);
            part[p3] = ((unsigned int)(d4.w & (BNODES - 1)) << 24) | (unsigned int)s4.w;
        } else {
            for (int t = 0; t < 4; t++)
                if (e + t < E) {
                    int d = dst[e + t];
                    int pos = atomicAdd(&cur[d >> BSHIFT], 1);
                    part[pos] = ((unsigned int)(d & (BNODES - 1)) << 24) | (unsigned int)src[e + t];
                }
        }
    }
}

// ---------- pass 2: per-bucket counting sort -> PADDED csr at fixed stride b*CAPP ----------
__global__ __launch_bounds__(256) void csr_build(const unsigned int* __restrict__ part,
                                                 const int* __restrict__ bucket_cursor,
                                                 int* __restrict__ csr_src,
                                                 int* __restrict__ row_ptr,
                                                 int* __restrict__ row_len,
                                                 float* __restrict__ dis,
                                                 int N) {
    __shared__ unsigned int eL[CAP];
    __shared__ unsigned int outL[CAP + PADB];
    __shared__ int cnt[BNODES];
    __shared__ int sc[BNODES];
    __shared__ int cur[BNODES];
    int tid = threadIdx.x;
    int b = blockIdx.x;
    int eB = b * CAP;               // fixed part slot
    int eN = bucket_cursor[b];      // final cursor = bucket count
    if (eN > CAP) eN = CAP;
    int pb = b * CAPP;              // fixed csr slot (CAPP multiple of 4 -> aligned)

    cnt[tid] = 0;
    __syncthreads();
    for (int i = tid; i < eN; i += 256) {
        unsigned int v = part[eB + i];
        eL[i] = v;
        atomicAdd(&cnt[v >> 24], 1);
    }
    // sentinel-init the padded output region (real edges overwrite below)
    for (int i = tid; i < eN + PADB; i += 256) outL[i] = (unsigned int)N;
    __syncthreads();
    int myc = cnt[tid];
    int pd = (myc + 3) & ~3;        // padded row length (multiple of 4)
    sc[tid] = pd;
    __syncthreads();
    for (int off = 1; off < 256; off <<= 1) {
        int t = (tid >= off) ? sc[tid - off] : 0;
        __syncthreads();
        sc[tid] += t;
        __syncthreads();
    }
    int excl = sc[tid] - pd;        // multiple of 4
    cur[tid] = excl;
    int gnode = b * BNODES + tid;
    if (gnode < N) {
        row_ptr[gnode] = pb + excl;  // 4-aligned: pb aligned + excl mult of 4
        row_len[gnode] = pd;
        float d = (float)myc;
        dis[gnode] = d > 0.0f ? rsqrtf(fmaxf(d, 1.0f)) : 0.0f;
    }
    __syncthreads();
    int pTot = sc[BNODES - 1];      // padded bucket total (<= eN + PADB)
    for (int i = tid; i < eN; i += 256) {
        unsigned int v = eL[i];
        int pos = atomicAdd(&cur[v >> 24], 1);
        outL[pos] = v & 0xFFFFFFu;
    }
    __syncthreads();
    for (int i = tid; i < pTot; i += 256)
        csr_src[pb + i] = (int)outL[i];
}

// ---------- gemm1 via MFMA bf16: 64 rows/block; also emits zeroed sentinel row N ----------
__global__ __launch_bounds__(256) void gemm1_kernel(
        const float* __restrict__ x, const unsigned short* __restrict__ w1t,
        const float* __restrict__ dis, unsigned short* __restrict__ h1b, int N) {
    __shared__ unsigned short xs[64][136];
    __shared__ unsigned short wsb[64][136];
    __shared__ float diss[64];
    int tid = threadIdx.x;
    int w = tid >> 6;
    int lane = tid & 63;
    int row0 = blockIdx.x * 64;

    #pragma unroll
    for (int it = 0; it < 8; it++) {
        int f = it * 256 + tid;
        int r = f >> 5, c = f & 31;
        float4 v = make_float4(0.f, 0.f, 0.f, 0.f);
        if (row0 + r < N) v = ((const float4*)x)[(size_t)(row0 + r) * 32 + c];
        unsigned int p0 = (unsigned int)f2bf(v.x) | ((unsigned int)f2bf(v.y) << 16);
        unsigned int p1 = (unsigned int)f2bf(v.z) | ((unsigned int)f2bf(v.w) << 16);
        *(uint2*)&xs[r][c * 4] = make_uint2(p0, p1);
    }
    #pragma unroll
    for (int it = 0; it < 4; it++) {
        int f = it * 256 + tid;
        int r = f >> 4, c = f & 15;
        *(uint4*)&wsb[r][c * 8] = ((const uint4*)w1t)[f];
    }
    if (tid < 64) diss[tid] = (row0 + tid < N) ? dis[row0 + tid] : 0.f;
    __syncthreads();

    int q = lane >> 4;
    int l15 = lane & 15;
    f32x4 acc[4] = {{0,0,0,0},{0,0,0,0},{0,0,0,0},{0,0,0,0}};
    bf16x8 a[4];
    #pragma unroll
    for (int kk = 0; kk < 4; kk++)
        a[kk] = *(const bf16x8*)&xs[w * 16 + l15][kk * 32 + q * 8];
    #pragma unroll
    for (int kk = 0; kk < 4; kk++) {
        #pragma unroll
        for (int ct = 0; ct < 4; ct++) {
            bf16x8 b = *(const bf16x8*)&wsb[ct * 16 + l15][kk * 32 + q * 8];
            acc[ct] = __builtin_amdgcn_mfma_f32_16x16x32_bf16(a[kk], b, acc[ct], 0, 0, 0);
        }
    }
    __syncthreads();
    #pragma unroll
    for (int ct = 0; ct < 4; ct++) {
        #pragma unroll
        for (int r = 0; r < 4; r++) {
            int m = w * 16 + q * 4 + r;
            xs[m][ct * 16 + l15] = f2bf(acc[ct][r] * diss[m]);
        }
    }
    __syncthreads();
    #pragma unroll
    for (int it = 0; it < 2; it++) {
        int f = it * 256 + tid;
        int r = f >> 3, c = f & 7;
        if (row0 + r < N + 1)   // row N written as zeros (diss=0) -> gather sentinel
            ((uint4*)&h1b[(size_t)(row0 + r) * HID])[c] = *(const uint4*)&xs[r][c * 8];
    }
}

// ---------- fused layer-1 agg + ReLU + W2 GEMM ----------
// 2 nodes/wave (half-wave each: 4 slots x 8 dim-lanes); padded CSR rows (4-aligned):
// 2 int4 index loads + 2 vector sentinel-selects + 8 independent 16B gathers per lane.
__global__ __launch_bounds__(256) void agg1_fused(
        const int* __restrict__ row_ptr, const int* __restrict__ row_len,
        const int* __restrict__ csr_src,
        const unsigned short* __restrict__ h1b, const float* __restrict__ dis,
        const float* __restrict__ b1, const float* __restrict__ W2,
        unsigned short* __restrict__ h2b, int N) {
    __shared__ float W2t[NCLS][HID + 4];   // transposed, padded row stride 68
    __shared__ float ts[8][HID];
    int tid = threadIdx.x;
    int w = tid >> 6;
    int lane = tid & 63;
    int half = lane >> 5;      // node within wave
    int hl = lane & 31;        // lane within half
    int sub = hl & 7;          // dims sub*8 .. sub*8+7 (16B)
    int slot = hl >> 3;        // edge slot 0..3 (each owns 2 int4 runs)
    int n = blockIdx.x * 8 + w * 2 + half;
    int nc = (n < N) ? n : 0;  // clamp so tail lanes still load safely

    // issue row_ptr/row_len/dis + vector index loads BEFORE LDS staging
    int start = row_ptr[nc];   // 4-aligned by construction
    int plen = row_len[nc];    // multiple of 4
    float dn = dis[nc];
    const int4* ip = (const int4*)(csr_src + start);
    int4 q0 = ip[2 * slot];
    int4 q1 = ip[2 * slot + 1];

    for (int i = tid; i < HID * NCLS; i += 256) W2t[i & 15][i >> 4] = W2[i];
    __syncthreads();
    if (n >= N) return;        // after the only __syncthreads (no barrier below)

    // vector sentinel-select: plen % 4 == 0, one compare covers a whole int4
    int e0 = slot * 8;
    if (e0 >= plen)     q0 = make_int4(N, N, N, N);
    if (e0 + 4 >= plen) q1 = make_int4(N, N, N, N);
    const unsigned short* hp = h1b + sub * 8;
    uint4 v0 = *(const uint4*)(hp + (unsigned)q0.x * HID);
    uint4 v1 = *(const uint4*)(hp + (unsigned)q0.y * HID);
    uint4 v2 = *(const uint4*)(hp + (unsigned)q0.z * HID);
    uint4 v3 = *(const uint4*)(hp + (unsigned)q0.w * HID);
    uint4 v4 = *(const uint4*)(hp + (unsigned)q1.x * HID);
    uint4 v5 = *(const uint4*)(hp + (unsigned)q1.y * HID);
    uint4 v6 = *(const uint4*)(hp + (unsigned)q1.z * HID);
    uint4 v7 = *(const uint4*)(hp + (unsigned)q1.w * HID);
    f32x2 a0 = (bfpair(v0.x) + bfpair(v1.x)) + (bfpair(v2.x) + bfpair(v3.x));
    f32x2 a1 = (bfpair(v0.y) + bfpair(v1.y)) + (bfpair(v2.y) + bfpair(v3.y));
    f32x2 a2 = (bfpair(v0.z) + bfpair(v1.z)) + (bfpair(v2.z) + bfpair(v3.z));
    f32x2 a3 = (bfpair(v0.w) + bfpair(v1.w)) + (bfpair(v2.w) + bfpair(v3.w));
    a0 += (bfpair(v4.x) + bfpair(v5.x)) + (bfpair(v6.x) + bfpair(v7.x));
    a1 += (bfpair(v4.y) + bfpair(v5.y)) + (bfpair(v6.y) + bfpair(v7.y));
    a2 += (bfpair(v4.z) + bfpair(v5.z)) + (bfpair(v6.z) + bfpair(v7.z));
    a3 += (bfpair(v4.w) + bfpair(v5.w)) + (bfpair(v6.w) + bfpair(v7.w));
    // residual for rare rows with plen > 32 (sentinel entries included, harmless)
    for (int i = 32 + slot; i < plen; i += 4) {
        int s = csr_src[start + i];
        uint4 v = *(const uint4*)(hp + (unsigned)s * HID);
        a0 += bfpair(v.x);
        a1 += bfpair(v.y);
        a2 += bfpair(v.z);
        a3 += bfpair(v.w);
    }
    // reduce across the 4 slots (lane bits 3,4 — stays within the half)
    #pragma unroll
    for (int m = 8; m <= 16; m <<= 1) {
        a0.x += __shfl_xor(a0.x, m, 64); a0.y += __shfl_xor(a0.y, m, 64);
        a1.x += __shfl_xor(a1.x, m, 64); a1.y += __shfl_xor(a1.y, m, 64);
        a2.x += __shfl_xor(a2.x, m, 64); a2.y += __shfl_xor(a2.y, m, 64);
        a3.x += __shfl_xor(a3.x, m, 64); a3.y += __shfl_xor(a3.y, m, 64);
    }
    if (slot == 0) {
        float4 bl = ((const float4*)b1)[sub * 2];
        float4 bh = ((const float4*)b1)[sub * 2 + 1];
        float4 r0, r1;
        r0.x = fmaxf(fmaf(dn, a0.x, bl.x), 0.f);
        r0.y = fmaxf(fmaf(dn, a0.y, bl.y), 0.f);
        r0.z = fmaxf(fmaf(dn, a1.x, bl.z), 0.f);
        r0.w = fmaxf(fmaf(dn, a1.y, bl.w), 0.f);
        r1.x = fmaxf(fmaf(dn, a2.x, bh.x), 0.f);
        r1.y = fmaxf(fmaf(dn, a2.y, bh.y), 0.f);
        r1.z = fmaxf(fmaf(dn, a3.x, bh.z), 0.f);
        r1.w = fmaxf(fmaf(dn, a3.y, bh.w), 0.f);
        *(float4*)&ts[w * 2 + half][sub * 8] = r0;
        *(float4*)&ts[w * 2 + half][sub * 8 + 4] = r1;
    }
    // wave-local LDS round-trip (same wave writes+reads; compiler inserts lgkmcnt)
    int q = hl >> 4, c = hl & 15;       // q: K-half 0/1, c: output class
    const float* tp = &ts[w * 2 + half][q * 32];
    const float* wp = &W2t[c][q * 32];
    float4 t0 = *(const float4*)tp,        t1 = *(const float4*)(tp + 4);
    float4 t2 = *(const float4*)(tp + 8),  t3 = *(const float4*)(tp + 12);
    float4 t4 = *(const float4*)(tp + 16), t5 = *(const float4*)(tp + 20);
    float4 t6 = *(const float4*)(tp + 24), t7 = *(const float4*)(tp + 28);
    float4 u0 = *(const float4*)wp,        u1 = *(const float4*)(wp + 4);
    float4 u2 = *(const float4*)(wp + 8),  u3 = *(const float4*)(wp + 12);
    float4 u4 = *(const float4*)(wp + 16), u5 = *(const float4*)(wp + 20);
    float4 u6 = *(const float4*)(wp + 24), u7 = *(const float4*)(wp + 28);
    float p = t0.x * u0.x + t0.y * u0.y + t0.z * u0.z + t0.w * u0.w
            + t1.x * u1.x + t1.y * u1.y + t1.z * u1.z + t1.w * u1.w
            + t2.x * u2.x + t2.y * u2.y + t2.z * u2.z + t2.w * u2.w
            + t3.x * u3.x + t3.y * u3.y + t3.z * u3.z + t3.w * u3.w
            + t4.x * u4.x + t4.y * u4.y + t4.z * u4.z + t4.w * u4.w
            + t5.x * u5.x + t5.y * u5.y + t5.z * u5.z + t5.w * u5.w
            + t6.x * u6.x + t6.y * u6.y + t6.z * u6.z + t6.w * u6.w
            + t7.x * u7.x + t7.y * u7.y + t7.z * u7.z + t7.w * u7.w;
    p += __shfl_xor(p, 16, 64);         // combine the two K-halves
    if (hl < 16) h2b[(unsigned)n * NCLS + c] = f2bf(p * dn);
}

// ---------- fused layer-2 agg + epilogue ----------
// 8 nodes/wave (8 lanes each: 4 slots x 2 dim-lanes), padded CSR + int4 index loads
__global__ __launch_bounds__(256) void agg2_fused(
        const int* __restrict__ row_ptr, const int* __restrict__ row_len,
        const int* __restrict__ csr_src,
        const unsigned short* __restrict__ h2b, const float* __restrict__ dis,
        const float* __restrict__ b2, float* __restrict__ out, int N) {
    int t = blockIdx.x * 256 + threadIdx.x;
    int lane = t & 63;
    int grp = lane >> 3;         // node within wave (0..7)
    int gl = lane & 7;
    int slot = gl >> 1;          // edge slot 0..3
    int sub = gl & 1;            // dims sub*8 .. sub*8+7
    int n = (t >> 6) * 8 + grp;
    if (n >= N) return;          // uniform within each 8-lane group
    int start = row_ptr[n];
    int plen = row_len[n];
    const int4* ip = (const int4*)(csr_src + start);
    int4 q0 = ip[2 * slot];
    int4 q1 = ip[2 * slot + 1];
    int e0 = slot * 8;
    if (e0 >= plen)     q0 = make_int4(N, N, N, N);
    if (e0 + 4 >= plen) q1 = make_int4(N, N, N, N);
    const unsigned short* hp = h2b + sub * 8;
    uint4 v0 = *(const uint4*)(hp + (unsigned)q0.x * NCLS);
    uint4 v1 = *(const uint4*)(hp + (unsigned)q0.y * NCLS);
    uint4 v2 = *(const uint4*)(hp + (unsigned)q0.z * NCLS);
    uint4 v3 = *(const uint4*)(hp + (unsigned)q0.w * NCLS);
    uint4 v4 = *(const uint4*)(hp + (unsigned)q1.x * NCLS);
    uint4 v5 = *(const uint4*)(hp + (unsigned)q1.y * NCLS);
    uint4 v6 = *(const uint4*)(hp + (unsigned)q1.z * NCLS);
    uint4 v7 = *(const uint4*)(hp + (unsigned)q1.w * NCLS);
    f32x2 a0 = (bfpair(v0.x) + bfpair(v1.x)) + (bfpair(v2.x) + bfpair(v3.x));
    f32x2 a1 = (bfpair(v0.y) + bfpair(v1.y)) + (bfpair(v2.y) + bfpair(v3.y));
    f32x2 a2 = (bfpair(v0.z) + bfpair(v1.z)) + (bfpair(v2.z) + bfpair(v3.z));
    f32x2 a3 = (bfpair(v0.w) + bfpair(v1.w)) + (bfpair(v2.w) + bfpair(v3.w));
    a0 += (bfpair(v4.x) + bfpair(v5.x)) + (bfpair(v6.x) + bfpair(v7.x));
    a1 += (bfpair(v4.y) + bfpair(v5.y)) + (bfpair(v6.y) + bfpair(v7.y));
    a2 += (bfpair(v4.z) + bfpair(v5.z)) + (bfpair(v6.z) + bfpair(v7.z));
    a3 += (bfpair(v4.w) + bfpair(v5.w)) + (bfpair(v6.w) + bfpair(v7.w));
    for (int i = 32 + slot; i < plen; i += 4) {
        int s = csr_src[start + i];
        uint4 v = *(const uint4*)(hp + (unsigned)s * NCLS);
        a0 += bfpair(v.x);
        a1 += bfpair(v.y);
        a2 += bfpair(v.z);
        a3 += bfpair(v.w);
    }
    // reduce across 4 slots (lane bits 1,2 — stays inside the 8-lane group)
    #pragma unroll
    for (int m = 2; m <= 4; m <<= 1) {
        a0.x += __shfl_xor(a0.x, m, 64); a0.y += __shfl_xor(a0.y, m, 64);
        a1.x += __shfl_xor(a1.x, m, 64); a1.y += __shfl_xor(a1.y, m, 64);
        a2.x += __shfl_xor(a2.x, m, 64); a2.y += __shfl_xor(a2.y, m, 64);
        a3.x += __shfl_xor(a3.x, m, 64); a3.y += __shfl_xor(a3.y, m, 64);
    }
    if (slot == 0) {
        float dn = dis[n];
        float4 bl = ((const float4*)b2)[sub * 2];
        float4 bh = ((const float4*)b2)[sub * 2 + 1];
        float4 o0, o1;
        o0.x = fmaf(dn, a0.x, bl.x); o0.y = fmaf(dn, a0.y, bl.y);
        o0.z = fmaf(dn, a1.x, bl.z); o0.w = fmaf(dn, a1.y, bl.w);
        o1.x = fmaf(dn, a2.x, bh.x); o1.y = fmaf(dn, a2.y, bh.y);
        o1.z = fmaf(dn, a3.x, bh.z); o1.w = fmaf(dn, a3.y, bh.w);
        float* op = out + (unsigned)n * NCLS + sub * 8;
        *(float4*)op = o0;
        *(float4*)(op + 4) = o1;
    }
}

extern "C" void kernel_launch(void* const* d_in, const int* in_sizes, int n_in,
                              void* d_out, int out_size, void* d_ws, size_t ws_size,
                              hipStream_t stream) {
    const float* x   = (const float*)d_in[0];
    const int*   src = (const int*)  d_in[1];
    const int*   dst = (const int*)  d_in[2];
    const float* W1  = (const float*)d_in[3];
    const float* b1  = (const float*)d_in[4];
    const float* W2  = (const float*)d_in[5];
    const float* b2  = (const float*)d_in[6];
    float* out = (float*)d_out;
    int E = in_sizes[1];
    int N = in_sizes[0] / F_IN;
    int NB = (N + BNODES - 1) >> BSHIFT;
    int nchunks = (E + CHUNK - 1) / CHUNK;   // 208 for E=1.7M

    char* ws = (char*)d_ws;
    size_t off = 0;
    auto alloc = [&](size_t bytes) { size_t o = off; off = (off + bytes + 255) & ~(size_t)255; return (void*)(ws + o); };
    int*   bucket_cursor = (int*)  alloc((size_t)NB * 4);
    int*   row_ptr       = (int*)  alloc((size_t)(N + 1) * 4);
    int*   row_len       = (int*)  alloc((size_t)N * 4);
    int*   csr_src       = (int*)  alloc((size_t)NB * CAPP * 4);   // fixed-stride padded CSR
    float* dis           = (float*)alloc((size_t)N * 4);
    unsigned short* w1t  = (unsigned short*)alloc((size_t)F_IN * HID * 2);
    size_t h1b_bytes  = (size_t)(N + 1) * HID * 2;                 // 12.80 MB
    size_t part_bytes = (size_t)NB * CAP * 4;                      // 12.81 MB
    unsigned short* h1b  = (unsigned short*)alloc(h1b_bytes > part_bytes ? h1b_bytes : part_bytes);
    unsigned short* h2b  = (unsigned short*)alloc((size_t)(N + 1) * NCLS * 2); // +1 sentinel row
    // part[] aliases h1b: dead before gemm1 writes h1b (alloc = max of both sizes)
    unsigned int* part   = (unsigned int*)h1b;

    hipMemsetAsync(bucket_cursor, 0, (size_t)NB * 4, stream);  // capture-legal memset node
    w1t_kernel     <<<1, 256, 0, stream>>>(W1, w1t, h2b, N);
    scatter_kernel <<<nchunks, 256, 0, stream>>>(src, dst, bucket_cursor, part, E, NB);
    csr_build      <<<NB, 256, 0, stream>>>(part, bucket_cursor, csr_src, row_ptr, row_len, dis, N);
    gemm1_kernel   <<<(N + 64) / 64, 256, 0, stream>>>(x, w1t, dis, h1b, N);  // +1 covers row N
    agg1_fused     <<<(N + 7) / 8, 256, 0, stream>>>(row_ptr, row_len, csr_src, h1b, dis, b1, W2, h2b, N);
    agg2_fused     <<<(N + 31) / 32, 256, 0, stream>>>(row_ptr, row_len, csr_src, h2b, dis, b2, out, N);
}

// Round 14
// 196.321 us; speedup vs baseline: 1.0672x; 1.0043x over previous
//
#include <hip/hip_runtime.h>

#define F_IN 128
#define HID  64
#define NCLS 16

#define BSHIFT 8            // 256 nodes per bucket
#define BNODES 256
#define NB_MAX 512          // max buckets (N<=128k)
#define CHUNK  8192         // edges per partition block
#define CAP    8192         // fixed part[] slot per bucket (mean 4352, 50+ sigma margin)
#define PADB   772          // csr per-bucket padding slack: 256 rows * 3 + align
#define CAPP   (CAP + PADB) // fixed csr slot per bucket (8964, multiple of 4)

typedef __attribute__((ext_vector_type(2))) float f32x2;
typedef __attribute__((ext_vector_type(8))) short bf16x8;
typedef __attribute__((ext_vector_type(4))) float f32x4;

// round-to-nearest-even fp32 -> bf16
__device__ __forceinline__ unsigned short f2bf(float f) {
    unsigned int u = __float_as_uint(f);
    u += 0x7FFFu + ((u >> 16) & 1u);
    return (unsigned short)(u >> 16);
}
// one dword = 2 packed bf16 -> f32x2 (2 VALU unpack + packed add)
// NOTE: do NOT replace with __builtin_amdgcn_fdot2_f32_bf16 — it compiles on
// gfx950 but produces wrong numerics (round-9 failure, absmax 0.57).
__device__ __forceinline__ f32x2 bfpair(unsigned int u) {
    f32x2 r;
    r.x = __uint_as_float(u << 16);
    r.y = __uint_as_float(u & 0xFFFF0000u);
    return r;
}

// ---------- tiny kernel: W1 -> bf16 transpose + h2b sentinel row ----------
__global__ __launch_bounds__(256) void w1t_kernel(const float* __restrict__ W1,
                                                  unsigned short* __restrict__ w1t,
                                                  unsigned short* __restrict__ h2b, int N) {
    int tid = threadIdx.x;
    for (int i = tid; i < F_IN * HID; i += 256) {
        int k = i >> 6, n = i & 63;
        w1t[n * F_IN + k] = f2bf(W1[i]);
    }
    if (tid < NCLS) h2b[(size_t)N * NCLS + tid] = 0;   // zero sentinel row for agg2
}

// ---------- pass 1: self-reserving partition into FIXED-capacity buckets ----------
// part[b*CAP + ofs]; bucket_cursor zeroed by hipMemsetAsync. Within-bucket order is
// arrival order (nondeterministic) — csr_build counting-sorts by node anyway.
__global__ __launch_bounds__(256) void scatter_kernel(const int* __restrict__ src,
                                                      const int* __restrict__ dst,
                                                      int* __restrict__ bucket_cursor,
                                                      unsigned int* __restrict__ part,
                                                      int E, int NB) {
    __shared__ int cnt[NB_MAX];
    __shared__ int cur[NB_MAX];
    int tid = threadIdx.x;
    int blk = blockIdx.x;
    for (int i = tid; i < NB; i += 256) cnt[i] = 0;
    __syncthreads();
    int cb = blk * CHUNK;
    #pragma unroll
    for (int k = 0; k < CHUNK / 1024; k++) {   // pass A: count own chunk
        int e = cb + (k * 256 + tid) * 4;
        if (e + 3 < E) {
            int4 d4 = *(const int4*)&dst[e];
            atomicAdd(&cnt[d4.x >> BSHIFT], 1);
            atomicAdd(&cnt[d4.y >> BSHIFT], 1);
            atomicAdd(&cnt[d4.z >> BSHIFT], 1);
            atomicAdd(&cnt[d4.w >> BSHIFT], 1);
        } else {
            for (int t = 0; t < 4; t++)
                if (e + t < E) atomicAdd(&cnt[dst[e + t] >> BSHIFT], 1);
        }
    }
    __syncthreads();
    for (int i = tid; i < NB; i += 256) {       // reserve ranges in fixed slots
        int c = cnt[i];
        cur[i] = i * CAP + (c ? atomicAdd(&bucket_cursor[i], c) : 0);
    }
    __syncthreads();
    #pragma unroll
    for (int k = 0; k < CHUNK / 1024; k++) {   // pass B: scatter (dst re-read L2-hot)
        int e = cb + (k * 256 + tid) * 4;
        if (e + 3 < E) {
            int4 d4 = *(const int4*)&dst[e];
            int4 s4 = *(const int4*)&src[e];
            int p0 = atomicAdd(&cur[d4.x >> BSHIFT], 1);
            part[p0] = ((unsigned int)(d4.x & (BNODES - 1)) << 24) | (unsigned int)s4.x;
            int p1 = atomicAdd(&cur[d4.y >> BSHIFT], 1);
            part[p1] = ((unsigned int)(d4.y & (BNODES - 1)) << 24) | (unsigned int)s4.y;
            int p2 = atomicAdd(&cur[d4.z >> BSHIFT], 1);
            part[p2] = ((unsigned int)(d4.z & (BNODES - 1)) << 24) | (unsigned int)s4.z;
            int p3 = atomicAdd(&cur[d4.w >> BSHIFT], 1);
            part[p3] = ((unsigned int)(d4.w & (BNODES - 1)) << 24) | (unsigned int)s4.w;
        } else {
            for (int t = 0; t < 4; t++)
                if (e + t < E) {
                    int d = dst[e + t];
                    int pos = atomicAdd(&cur[d >> BSHIFT], 1);
                    part[pos] = ((unsigned int)(d & (BNODES - 1)) << 24) | (unsigned int)src[e + t];
                }
        }
    }
}

// ---------- pass 2: per-bucket counting sort -> PADDED csr at fixed stride b*CAPP ----------
// 512 threads: halves every stride loop vs 256 (LDS 71KB -> still 2 blocks/CU)
__global__ __launch_bounds__(512) void csr_build(const unsigned int* __restrict__ part,
                                                 const int* __restrict__ bucket_cursor,
                                                 int* __restrict__ csr_src,
                                                 int4* __restrict__ rowmeta,
                                                 float* __restrict__ dis,
                                                 int N) {
    __shared__ unsigned int eL[CAP];
    __shared__ unsigned int outL[CAP + PADB];
    __shared__ int cnt[BNODES];
    __shared__ int sc[BNODES];
    __shared__ int cur[BNODES];
    int tid = threadIdx.x;
    int b = blockIdx.x;
    int eB = b * CAP;               // fixed part slot
    int eN = bucket_cursor[b];      // final cursor = bucket count
    if (eN > CAP) eN = CAP;
    int pb = b * CAPP;              // fixed csr slot (CAPP multiple of 4 -> aligned)

    if (tid < BNODES) cnt[tid] = 0;
    __syncthreads();
    for (int i = tid; i < eN; i += 512) {
        unsigned int v = part[eB + i];
        eL[i] = v;
        atomicAdd(&cnt[v >> 24], 1);
    }
    // sentinel-init the padded output region (real edges overwrite below)
    for (int i = tid; i < eN + PADB; i += 512) outL[i] = (unsigned int)N;
    __syncthreads();
    int myc = 0, pd = 0;
    if (tid < BNODES) {
        myc = cnt[tid];
        pd = (myc + 3) & ~3;        // padded row length (multiple of 4)
        sc[tid] = pd;
    }
    __syncthreads();
    for (int off = 1; off < 256; off <<= 1) {
        int t = (tid >= off && tid < BNODES) ? sc[tid - off] : 0;
        __syncthreads();
        if (tid < BNODES) sc[tid] += t;
        __syncthreads();
    }
    if (tid < BNODES) {
        int excl = sc[tid] - pd;    // multiple of 4
        cur[tid] = excl;
        int gnode = b * BNODES + tid;
        if (gnode < N) {
            float d = (float)myc;
            float dv = d > 0.0f ? rsqrtf(fmaxf(d, 1.0f)) : 0.0f;
            rowmeta[gnode] = make_int4(pb + excl, pd, __float_as_int(dv), 0);
            dis[gnode] = dv;
        }
    }
    __syncthreads();
    int pTot = sc[BNODES - 1];      // padded bucket total (<= eN + PADB)
    for (int i = tid; i < eN; i += 512) {
        unsigned int v = eL[i];
        int pos = atomicAdd(&cur[v >> 24], 1);
        outL[pos] = v & 0xFFFFFFu;
    }
    __syncthreads();
    for (int i = tid; i < pTot; i += 512)
        csr_src[pb + i] = (int)outL[i];
}

// ---------- gemm1 via MFMA bf16: 64 rows/block; also emits zeroed sentinel row N ----------
__global__ __launch_bounds__(256) void gemm1_kernel(
        const float* __restrict__ x, const unsigned short* __restrict__ w1t,
        const float* __restrict__ dis, unsigned short* __restrict__ h1b, int N) {
    __shared__ unsigned short xs[64][136];
    __shared__ unsigned short wsb[64][136];
    __shared__ float diss[64];
    int tid = threadIdx.x;
    int w = tid >> 6;
    int lane = tid & 63;
    int row0 = blockIdx.x * 64;

    #pragma unroll
    for (int it = 0; it < 8; it++) {
        int f = it * 256 + tid;
        int r = f >> 5, c = f & 31;
        float4 v = make_float4(0.f, 0.f, 0.f, 0.f);
        if (row0 + r < N) v = ((const float4*)x)[(size_t)(row0 + r) * 32 + c];
        unsigned int p0 = (unsigned int)f2bf(v.x) | ((unsigned int)f2bf(v.y) << 16);
        unsigned int p1 = (unsigned int)f2bf(v.z) | ((unsigned int)f2bf(v.w) << 16);
        *(uint2*)&xs[r][c * 4] = make_uint2(p0, p1);
    }
    #pragma unroll
    for (int it = 0; it < 4; it++) {
        int f = it * 256 + tid;
        int r = f >> 4, c = f & 15;
        *(uint4*)&wsb[r][c * 8] = ((const uint4*)w1t)[f];
    }
    if (tid < 64) diss[tid] = (row0 + tid < N) ? dis[row0 + tid] : 0.f;
    __syncthreads();

    int q = lane >> 4;
    int l15 = lane & 15;
    f32x4 acc[4] = {{0,0,0,0},{0,0,0,0},{0,0,0,0},{0,0,0,0}};
    bf16x8 a[4];
    #pragma unroll
    for (int kk = 0; kk < 4; kk++)
        a[kk] = *(const bf16x8*)&xs[w * 16 + l15][kk * 32 + q * 8];
    #pragma unroll
    for (int kk = 0; kk < 4; kk++) {
        #pragma unroll
        for (int ct = 0; ct < 4; ct++) {
            bf16x8 b = *(const bf16x8*)&wsb[ct * 16 + l15][kk * 32 + q * 8];
            acc[ct] = __builtin_amdgcn_mfma_f32_16x16x32_bf16(a[kk], b, acc[ct], 0, 0, 0);
        }
    }
    __syncthreads();
    #pragma unroll
    for (int ct = 0; ct < 4; ct++) {
        #pragma unroll
        for (int r = 0; r < 4; r++) {
            int m = w * 16 + q * 4 + r;
            xs[m][ct * 16 + l15] = f2bf(acc[ct][r] * diss[m]);
        }
    }
    __syncthreads();
    #pragma unroll
    for (int it = 0; it < 2; it++) {
        int f = it * 256 + tid;
        int r = f >> 3, c = f & 7;
        if (row0 + r < N + 1)   // row N written as zeros (diss=0) -> gather sentinel
            ((uint4*)&h1b[(size_t)(row0 + r) * HID])[c] = *(const uint4*)&xs[r][c * 8];
    }
}

// ---------- fused layer-1 agg + ReLU + W2 GEMM ----------
// 2 nodes/wave (half-wave each: 4 slots x 8 dim-lanes); padded CSR rows (4-aligned):
// 1 int4 rowmeta load + 2 int4 index loads + 2 vector sentinel-selects + 8 16B gathers.
__global__ __launch_bounds__(256) void agg1_fused(
        const int4* __restrict__ rowmeta, const int* __restrict__ csr_src,
        const unsigned short* __restrict__ h1b,
        const float* __restrict__ b1, const float* __restrict__ W2,
        unsigned short* __restrict__ h2b, int N) {
    __shared__ float W2t[NCLS][HID + 4];   // transposed, padded row stride 68
    __shared__ float ts[8][HID];
    int tid = threadIdx.x;
    int w = tid >> 6;
    int lane = tid & 63;
    int half = lane >> 5;      // node within wave
    int hl = lane & 31;        // lane within half
    int sub = hl & 7;          // dims sub*8 .. sub*8+7 (16B)
    int slot = hl >> 3;        // edge slot 0..3 (each owns 2 int4 runs)
    int n = blockIdx.x * 8 + w * 2 + half;
    int nc = (n < N) ? n : 0;  // clamp so tail lanes still load safely

    // single 16B rowmeta load + vector index loads BEFORE LDS staging
    int4 meta = rowmeta[nc];
    int start = meta.x;        // 4-aligned by construction
    int plen = meta.y;         // multiple of 4
    float dn = __int_as_float(meta.z);
    const int4* ip = (const int4*)(csr_src + start);
    int4 q0 = ip[2 * slot];
    int4 q1 = ip[2 * slot + 1];

    for (int i = tid; i < HID * NCLS; i += 256) W2t[i & 15][i >> 4] = W2[i];
    __syncthreads();
    if (n >= N) return;        // after the only __syncthreads (no barrier below)

    // vector sentinel-select: plen % 4 == 0, one compare covers a whole int4
    int e0 = slot * 8;
    if (e0 >= plen)     q0 = make_int4(N, N, N, N);
    if (e0 + 4 >= plen) q1 = make_int4(N, N, N, N);
    const unsigned short* hp = h1b + sub * 8;
    uint4 v0 = *(const uint4*)(hp + (unsigned)q0.x * HID);
    uint4 v1 = *(const uint4*)(hp + (unsigned)q0.y * HID);
    uint4 v2 = *(const uint4*)(hp + (unsigned)q0.z * HID);
    uint4 v3 = *(const uint4*)(hp + (unsigned)q0.w * HID);
    uint4 v4 = *(const uint4*)(hp + (unsigned)q1.x * HID);
    uint4 v5 = *(const uint4*)(hp + (unsigned)q1.y * HID);
    uint4 v6 = *(const uint4*)(hp + (unsigned)q1.z * HID);
    uint4 v7 = *(const uint4*)(hp + (unsigned)q1.w * HID);
    f32x2 a0 = (bfpair(v0.x) + bfpair(v1.x)) + (bfpair(v2.x) + bfpair(v3.x));
    f32x2 a1 = (bfpair(v0.y) + bfpair(v1.y)) + (bfpair(v2.y) + bfpair(v3.y));
    f32x2 a2 = (bfpair(v0.z) + bfpair(v1.z)) + (bfpair(v2.z) + bfpair(v3.z));
    f32x2 a3 = (bfpair(v0.w) + bfpair(v1.w)) + (bfpair(v2.w) + bfpair(v3.w));
    a0 += (bfpair(v4.x) + bfpair(v5.x)) + (bfpair(v6.x) + bfpair(v7.x));
    a1 += (bfpair(v4.y) + bfpair(v5.y)) + (bfpair(v6.y) + bfpair(v7.y));
    a2 += (bfpair(v4.z) + bfpair(v5.z)) + (bfpair(v6.z) + bfpair(v7.z));
    a3 += (bfpair(v4.w) + bfpair(v5.w)) + (bfpair(v6.w) + bfpair(v7.w));
    // residual for rare rows with plen > 32 (sentinel entries included, harmless)
    for (int i = 32 + slot; i < plen; i += 4) {
        int s = csr_src[start + i];
        uint4 v = *(const uint4*)(hp + (unsigned)s * HID);
        a0 += bfpair(v.x);
        a1 += bfpair(v.y);
        a2 += bfpair(v.z);
        a3 += bfpair(v.w);
    }
    // reduce across the 4 slots (lane bits 3,4 — stays within the half)
    #pragma unroll
    for (int m = 8; m <= 16; m <<= 1) {
        a0.x += __shfl_xor(a0.x, m, 64); a0.y += __shfl_xor(a0.y, m, 64);
        a1.x += __shfl_xor(a1.x, m, 64); a1.y += __shfl_xor(a1.y, m, 64);
        a2.x += __shfl_xor(a2.x, m, 64); a2.y += __shfl_xor(a2.y, m, 64);
        a3.x += __shfl_xor(a3.x, m, 64); a3.y += __shfl_xor(a3.y, m, 64);
    }
    if (slot == 0) {
        float4 bl = ((const float4*)b1)[sub * 2];
        float4 bh = ((const float4*)b1)[sub * 2 + 1];
        float4 r0, r1;
        r0.x = fmaxf(fmaf(dn, a0.x, bl.x), 0.f);
        r0.y = fmaxf(fmaf(dn, a0.y, bl.y), 0.f);
        r0.z = fmaxf(fmaf(dn, a1.x, bl.z), 0.f);
        r0.w = fmaxf(fmaf(dn, a1.y, bl.w), 0.f);
        r1.x = fmaxf(fmaf(dn, a2.x, bh.x), 0.f);
        r1.y = fmaxf(fmaf(dn, a2.y, bh.y), 0.f);
        r1.z = fmaxf(fmaf(dn, a3.x, bh.z), 0.f);
        r1.w = fmaxf(fmaf(dn, a3.y, bh.w), 0.f);
        *(float4*)&ts[w * 2 + half][sub * 8] = r0;
        *(float4*)&ts[w * 2 + half][sub * 8 + 4] = r1;
    }
    // wave-local LDS round-trip (same wave writes+reads; compiler inserts lgkmcnt)
    int q = hl >> 4, c = hl & 15;       // q: K-half 0/1, c: output class
    const float* tp = &ts[w * 2 + half][q * 32];
    const float* wp = &W2t[c][q * 32];
    float4 t0 = *(const float4*)tp,        t1 = *(const float4*)(tp + 4);
    float4 t2 = *(const float4*)(tp + 8),  t3 = *(const float4*)(tp + 12);
    float4 t4 = *(const float4*)(tp + 16), t5 = *(const float4*)(tp + 20);
    float4 t6 = *(const float4*)(tp + 24), t7 = *(const float4*)(tp + 28);
    float4 u0 = *(const float4*)wp,        u1 = *(const float4*)(wp + 4);
    float4 u2 = *(const float4*)(wp + 8),  u3 = *(const float4*)(wp + 12);
    float4 u4 = *(const float4*)(wp + 16), u5 = *(const float4*)(wp + 20);
    float4 u6 = *(const float4*)(wp + 24), u7 = *(const float4*)(wp + 28);
    float p = t0.x * u0.x + t0.y * u0.y + t0.z * u0.z + t0.w * u0.w
            + t1.x * u1.x + t1.y * u1.y + t1.z * u1.z + t1.w * u1.w
            + t2.x * u2.x + t2.y * u2.y + t2.z * u2.z + t2.w * u2.w
            + t3.x * u3.x + t3.y * u3.y + t3.z * u3.z + t3.w * u3.w
            + t4.x * u4.x + t4.y * u4.y + t4.z * u4.z + t4.w * u4.w
            + t5.x * u5.x + t5.y * u5.y + t5.z * u5.z + t5.w * u5.w
            + t6.x * u6.x + t6.y * u6.y + t6.z * u6.z + t6.w * u6.w
            + t7.x * u7.x + t7.y * u7.y + t7.z * u7.z + t7.w * u7.w;
    p += __shfl_xor(p, 16, 64);         // combine the two K-halves
    if (hl < 16) h2b[(unsigned)n * NCLS + c] = f2bf(p * dn);
}

// ---------- fused layer-2 agg + epilogue ----------
// 8 nodes/wave (8 lanes each: 4 slots x 2 dim-lanes), padded CSR + rowmeta
__global__ __launch_bounds__(256) void agg2_fused(
        const int4* __restrict__ rowmeta, const int* __restrict__ csr_src,
        const unsigned short* __restrict__ h2b,
        const float* __restrict__ b2, float* __restrict__ out, int N) {
    int t = blockIdx.x * 256 + threadIdx.x;
    int lane = t & 63;
    int grp = lane >> 3;         // node within wave (0..7)
    int gl = lane & 7;
    int slot = gl >> 1;          // edge slot 0..3
    int sub = gl & 1;            // dims sub*8 .. sub*8+7
    int n = (t >> 6) * 8 + grp;
    if (n >= N) return;          // uniform within each 8-lane group
    int4 meta = rowmeta[n];
    int start = meta.x;
    int plen = meta.y;
    float dn = __int_as_float(meta.z);
    const int4* ip = (const int4*)(csr_src + start);
    int4 q0 = ip[2 * slot];
    int4 q1 = ip[2 * slot + 1];
    int e0 = slot * 8;
    if (e0 >= plen)     q0 = make_int4(N, N, N, N);
    if (e0 + 4 >= plen) q1 = make_int4(N, N, N, N);
    const unsigned short* hp = h2b + sub * 8;
    uint4 v0 = *(const uint4*)(hp + (unsigned)q0.x * NCLS);
    uint4 v1 = *(const uint4*)(hp + (unsigned)q0.y * NCLS);
    uint4 v2 = *(const uint4*)(hp + (unsigned)q0.z * NCLS);
    uint4 v3 = *(const uint4*)(hp + (unsigned)q0.w * NCLS);
    uint4 v4 = *(const uint4*)(hp + (unsigned)q1.x * NCLS);
    uint4 v5 = *(const uint4*)(hp + (unsigned)q1.y * NCLS);
    uint4 v6 = *(const uint4*)(hp + (unsigned)q1.z * NCLS);
    uint4 v7 = *(const uint4*)(hp + (unsigned)q1.w * NCLS);
    f32x2 a0 = (bfpair(v0.x) + bfpair(v1.x)) + (bfpair(v2.x) + bfpair(v3.x));
    f32x2 a1 = (bfpair(v0.y) + bfpair(v1.y)) + (bfpair(v2.y) + bfpair(v3.y));
    f32x2 a2 = (bfpair(v0.z) + bfpair(v1.z)) + (bfpair(v2.z) + bfpair(v3.z));
    f32x2 a3 = (bfpair(v0.w) + bfpair(v1.w)) + (bfpair(v2.w) + bfpair(v3.w));
    a0 += (bfpair(v4.x) + bfpair(v5.x)) + (bfpair(v6.x) + bfpair(v7.x));
    a1 += (bfpair(v4.y) + bfpair(v5.y)) + (bfpair(v6.y) + bfpair(v7.y));
    a2 += (bfpair(v4.z) + bfpair(v5.z)) + (bfpair(v6.z) + bfpair(v7.z));
    a3 += (bfpair(v4.w) + bfpair(v5.w)) + (bfpair(v6.w) + bfpair(v7.w));
    for (int i = 32 + slot; i < plen; i += 4) {
        int s = csr_src[start + i];
        uint4 v = *(const uint4*)(hp + (unsigned)s * NCLS);
        a0 += bfpair(v.x);
        a1 += bfpair(v.y);
        a2 += bfpair(v.z);
        a3 += bfpair(v.w);
    }
    // reduce across 4 slots (lane bits 1,2 — stays inside the 8-lane group)
    #pragma unroll
    for (int m = 2; m <= 4; m <<= 1) {
        a0.x += __shfl_xor(a0.x, m, 64); a0.y += __shfl_xor(a0.y, m, 64);
        a1.x += __shfl_xor(a1.x, m, 64); a1.y += __shfl_xor(a1.y, m, 64);
        a2.x += __shfl_xor(a2.x, m, 64); a2.y += __shfl_xor(a2.y, m, 64);
        a3.x += __shfl_xor(a3.x, m, 64); a3.y += __shfl_xor(a3.y, m, 64);
    }
    if (slot == 0) {
        float4 bl = ((const float4*)b2)[sub * 2];
        float4 bh = ((const float4*)b2)[sub * 2 + 1];
        float4 o0, o1;
        o0.x = fmaf(dn, a0.x, bl.x); o0.y = fmaf(dn, a0.y, bl.y);
        o0.z = fmaf(dn, a1.x, bl.z); o0.w = fmaf(dn, a1.y, bl.w);
        o1.x = fmaf(dn, a2.x, bh.x); o1.y = fmaf(dn, a2.y, bh.y);
        o1.z = fmaf(dn, a3.x, bh.z); o1.w = fmaf(dn, a3.y, bh.w);
        float* op = out + (unsigned)n * NCLS + sub * 8;
        *(float4*)op = o0;
        *(float4*)(op + 4) = o1;
    }
}

extern "C" void kernel_launch(void* const* d_in, const int* in_sizes, int n_in,
                              void* d_out, int out_size, void* d_ws, size_t ws_size,
                              hipStream_t stream) {
    const float* x   = (const float*)d_in[0];
    const int*   src = (const int*)  d_in[1];
    const int*   dst = (const int*)  d_in[2];
    const float* W1  = (const float*)d_in[3];
    const float* b1  = (const float*)d_in[4];
    const float* W2  = (const float*)d_in[5];
    const float* b2  = (const float*)d_in[6];
    float* out = (float*)d_out;
    int E = in_sizes[1];
    int N = in_sizes[0] / F_IN;
    int NB = (N + BNODES - 1) >> BSHIFT;
    int nchunks = (E + CHUNK - 1) / CHUNK;   // 208 for E=1.7M

    char* ws = (char*)d_ws;
    size_t off = 0;
    auto alloc = [&](size_t bytes) { size_t o = off; off = (off + bytes + 255) & ~(size_t)255; return (void*)(ws + o); };
    int*   bucket_cursor = (int*)  alloc((size_t)NB * 4);
    int4*  rowmeta       = (int4*) alloc((size_t)N * 16);
    int*   csr_src       = (int*)  alloc((size_t)NB * CAPP * 4);   // fixed-stride padded CSR
    float* dis           = (float*)alloc((size_t)N * 4);
    unsigned short* w1t  = (unsigned short*)alloc((size_t)F_IN * HID * 2);
    size_t h1b_bytes  = (size_t)(N + 1) * HID * 2;                 // 12.80 MB
    size_t part_bytes = (size_t)NB * CAP * 4;                      // 12.81 MB
    unsigned short* h1b  = (unsigned short*)alloc(h1b_bytes > part_bytes ? h1b_bytes : part_bytes);
    unsigned short* h2b  = (unsigned short*)alloc((size_t)(N + 1) * NCLS * 2); // +1 sentinel row
    // part[] aliases h1b: dead before gemm1 writes h1b (alloc = max of both sizes)
    unsigned int* part   = (unsigned int*)h1b;

    hipMemsetAsync(bucket_cursor, 0, (size_t)NB * 4, stream);  // capture-legal memset node
    w1t_kernel     <<<1, 256, 0, stream>>>(W1, w1t, h2b, N);
    scatter_kernel <<<nchunks, 256, 0, stream>>>(src, dst, bucket_cursor, part, E, NB);
    csr_build      <<<NB, 512, 0, stream>>>(part, bucket_cursor, csr_src, rowmeta, dis, N);
    gemm1_kernel   <<<(N + 64) / 64, 256, 0, stream>>>(x, w1t, dis, h1b, N);  // +1 covers row N
    agg1_fused     <<<(N + 7) / 8, 256, 0, stream>>>(rowmeta, csr_src, h1b, b1, W2, h2b, N);
    agg2_fused     <<<(N + 31) / 32, 256, 0, stream>>>(rowmeta, csr_src, h2b, b2, out, N);
}

// Round 15
// 193.129 us; speedup vs baseline: 1.0848x; 1.0165x over previous
//
#include <hip/hip_runtime.h>

#define F_IN 128
#define HID  64
#define NCLS 16

#define BSHIFT 8            // 256 nodes per bucket
#define BNODES 256
#define NB_MAX 512          // max buckets (N<=128k)
#define CHUNK  8192         // edges per partition block
#define CAP    8192         // fixed part[] slot per bucket (mean 4352, 50+ sigma margin)
#define PADB   772          // csr per-bucket padding slack: 256 rows * 3 + align
#define CAPP   (CAP + PADB) // fixed csr slot per bucket (8964, multiple of 4)

typedef __attribute__((ext_vector_type(2))) float f32x2;
typedef __attribute__((ext_vector_type(8))) short bf16x8;
typedef __attribute__((ext_vector_type(4))) float f32x4;

// round-to-nearest-even fp32 -> bf16
__device__ __forceinline__ unsigned short f2bf(float f) {
    unsigned int u = __float_as_uint(f);
    u += 0x7FFFu + ((u >> 16) & 1u);
    return (unsigned short)(u >> 16);
}
// one dword = 2 packed bf16 -> f32x2 (2 VALU unpack + packed add)
// NOTE: do NOT replace with __builtin_amdgcn_fdot2_f32_bf16 — it compiles on
// gfx950 but produces wrong numerics (round-9 failure, absmax 0.57).
__device__ __forceinline__ f32x2 bfpair(unsigned int u) {
    f32x2 r;
    r.x = __uint_as_float(u << 16);
    r.y = __uint_as_float(u & 0xFFFF0000u);
    return r;
}

// ---------- tiny kernel: W1 -> bf16 transpose + h2b sentinel row ----------
__global__ __launch_bounds__(256) void w1t_kernel(const float* __restrict__ W1,
                                                  unsigned short* __restrict__ w1t,
                                                  unsigned short* __restrict__ h2b, int N) {
    int tid = threadIdx.x;
    for (int i = tid; i < F_IN * HID; i += 256) {
        int k = i >> 6, n = i & 63;
        w1t[n * F_IN + k] = f2bf(W1[i]);
    }
    if (tid < NCLS) h2b[(size_t)N * NCLS + tid] = 0;   // zero sentinel row for agg2
}

// ---------- pass 1: self-reserving partition into FIXED-capacity buckets ----------
// part[b*CAP + ofs]; bucket_cursor zeroed by hipMemsetAsync. Within-bucket order is
// arrival order (nondeterministic) — csr_build counting-sorts by node anyway.
__global__ __launch_bounds__(256) void scatter_kernel(const int* __restrict__ src,
                                                      const int* __restrict__ dst,
                                                      int* __restrict__ bucket_cursor,
                                                      unsigned int* __restrict__ part,
                                                      int E, int NB) {
    __shared__ int cnt[NB_MAX];
    __shared__ int cur[NB_MAX];
    int tid = threadIdx.x;
    int blk = blockIdx.x;
    for (int i = tid; i < NB; i += 256) cnt[i] = 0;
    __syncthreads();
    int cb = blk * CHUNK;
    #pragma unroll
    for (int k = 0; k < CHUNK / 1024; k++) {   // pass A: count own chunk
        int e = cb + (k * 256 + tid) * 4;
        if (e + 3 < E) {
            int4 d4 = *(const int4*)&dst[e];
            atomicAdd(&cnt[d4.x >> BSHIFT], 1);
            atomicAdd(&cnt[d4.y >> BSHIFT], 1);
            atomicAdd(&cnt[d4.z >> BSHIFT], 1);
            atomicAdd(&cnt[d4.w >> BSHIFT], 1);
        } else {
            for (int t = 0; t < 4; t++)
                if (e + t < E) atomicAdd(&cnt[dst[e + t] >> BSHIFT], 1);
        }
    }
    __syncthreads();
    for (int i = tid; i < NB; i += 256) {       // reserve ranges in fixed slots
        int c = cnt[i];
        cur[i] = i * CAP + (c ? atomicAdd(&bucket_cursor[i], c) : 0);
    }
    __syncthreads();
    #pragma unroll
    for (int k = 0; k < CHUNK / 1024; k++) {   // pass B: scatter (dst re-read L2-hot)
        int e = cb + (k * 256 + tid) * 4;
        if (e + 3 < E) {
            int4 d4 = *(const int4*)&dst[e];
            int4 s4 = *(const int4*)&src[e];
            int p0 = atomicAdd(&cur[d4.x >> BSHIFT], 1);
            part[p0] = ((unsigned int)(d4.x & (BNODES - 1)) << 24) | (unsigned int)s4.x;
            int p1 = atomicAdd(&cur[d4.y >> BSHIFT], 1);
            part[p1] = ((unsigned int)(d4.y & (BNODES - 1)) << 24) | (unsigned int)s4.y;
            int p2 = atomicAdd(&cur[d4.z >> BSHIFT], 1);
            part[p2] = ((unsigned int)(d4.z & (BNODES - 1)) << 24) | (unsigned int)s4.z;
            int p3 = atomicAdd(&cur[d4.w >> BSHIFT], 1);
            part[p3] = ((unsigned int)(d4.w & (BNODES - 1)) << 24) | (unsigned int)s4.w;
        } else {
            for (int t = 0; t < 4; t++)
                if (e + t < E) {
                    int d = dst[e + t];
                    int pos = atomicAdd(&cur[d >> BSHIFT], 1);
                    part[pos] = ((unsigned int)(d & (BNODES - 1)) << 24) | (unsigned int)src[e + t];
                }
        }
    }
}

// ---------- pass 2: per-bucket counting sort -> PADDED csr at fixed stride b*CAPP ----------
// 512 threads: halves every stride loop vs 256 (LDS 71KB -> still 2 blocks/CU)
__global__ __launch_bounds__(512) void csr_build(const unsigned int* __restrict__ part,
                                                 const int* __restrict__ bucket_cursor,
                                                 int* __restrict__ csr_src,
                                                 int4* __restrict__ rowmeta,
                                                 float* __restrict__ dis,
                                                 int N) {
    __shared__ unsigned int eL[CAP];
    __shared__ unsigned int outL[CAP + PADB];
    __shared__ int cnt[BNODES];
    __shared__ int sc[BNODES];
    __shared__ int cur[BNODES];
    int tid = threadIdx.x;
    int b = blockIdx.x;
    int eB = b * CAP;               // fixed part slot
    int eN = bucket_cursor[b];      // final cursor = bucket count
    if (eN > CAP) eN = CAP;
    int pb = b * CAPP;              // fixed csr slot (CAPP multiple of 4 -> aligned)

    if (tid < BNODES) cnt[tid] = 0;
    __syncthreads();
    for (int i = tid; i < eN; i += 512) {
        unsigned int v = part[eB + i];
        eL[i] = v;
        atomicAdd(&cnt[v >> 24], 1);
    }
    // sentinel-init the padded output region (real edges overwrite below)
    for (int i = tid; i < eN + PADB; i += 512) outL[i] = (unsigned int)N;
    __syncthreads();
    int myc = 0, pd = 0;
    if (tid < BNODES) {
        myc = cnt[tid];
        pd = (myc + 3) & ~3;        // padded row length (multiple of 4)
        sc[tid] = pd;
    }
    __syncthreads();
    for (int off = 1; off < 256; off <<= 1) {
        int t = (tid >= off && tid < BNODES) ? sc[tid - off] : 0;
        __syncthreads();
        if (tid < BNODES) sc[tid] += t;
        __syncthreads();
    }
    if (tid < BNODES) {
        int excl = sc[tid] - pd;    // multiple of 4
        cur[tid] = excl;
        int gnode = b * BNODES + tid;
        if (gnode < N) {
            float d = (float)myc;
            float dv = d > 0.0f ? rsqrtf(fmaxf(d, 1.0f)) : 0.0f;
            rowmeta[gnode] = make_int4(pb + excl, pd, __float_as_int(dv), 0);
            dis[gnode] = dv;
        }
    }
    __syncthreads();
    int pTot = sc[BNODES - 1];      // padded bucket total (<= eN + PADB)
    for (int i = tid; i < eN; i += 512) {
        unsigned int v = eL[i];
        int pos = atomicAdd(&cur[v >> 24], 1);
        outL[pos] = v & 0xFFFFFFu;
    }
    __syncthreads();
    for (int i = tid; i < pTot; i += 512)
        csr_src[pb + i] = (int)outL[i];
}

// ---------- gemm1 via MFMA bf16: 64 rows/block; also emits zeroed sentinel row N ----------
__global__ __launch_bounds__(256) void gemm1_kernel(
        const float* __restrict__ x, const unsigned short* __restrict__ w1t,
        const float* __restrict__ dis, unsigned short* __restrict__ h1b, int N) {
    __shared__ unsigned short xs[64][136];
    __shared__ unsigned short wsb[64][136];
    __shared__ float diss[64];
    int tid = threadIdx.x;
    int w = tid >> 6;
    int lane = tid & 63;
    int row0 = blockIdx.x * 64;

    #pragma unroll
    for (int it = 0; it < 8; it++) {
        int f = it * 256 + tid;
        int r = f >> 5, c = f & 31;
        float4 v = make_float4(0.f, 0.f, 0.f, 0.f);
        if (row0 + r < N) v = ((const float4*)x)[(size_t)(row0 + r) * 32 + c];
        unsigned int p0 = (unsigned int)f2bf(v.x) | ((unsigned int)f2bf(v.y) << 16);
        unsigned int p1 = (unsigned int)f2bf(v.z) | ((unsigned int)f2bf(v.w) << 16);
        *(uint2*)&xs[r][c * 4] = make_uint2(p0, p1);
    }
    #pragma unroll
    for (int it = 0; it < 4; it++) {
        int f = it * 256 + tid;
        int r = f >> 4, c = f & 15;
        *(uint4*)&wsb[r][c * 8] = ((const uint4*)w1t)[f];
    }
    if (tid < 64) diss[tid] = (row0 + tid < N) ? dis[row0 + tid] : 0.f;
    __syncthreads();

    int q = lane >> 4;
    int l15 = lane & 15;
    f32x4 acc[4] = {{0,0,0,0},{0,0,0,0},{0,0,0,0},{0,0,0,0}};
    bf16x8 a[4];
    #pragma unroll
    for (int kk = 0; kk < 4; kk++)
        a[kk] = *(const bf16x8*)&xs[w * 16 + l15][kk * 32 + q * 8];
    #pragma unroll
    for (int kk = 0; kk < 4; kk++) {
        #pragma unroll
        for (int ct = 0; ct < 4; ct++) {
            bf16x8 b = *(const bf16x8*)&wsb[ct * 16 + l15][kk * 32 + q * 8];
            acc[ct] = __builtin_amdgcn_mfma_f32_16x16x32_bf16(a[kk], b, acc[ct], 0, 0, 0);
        }
    }
    __syncthreads();
    #pragma unroll
    for (int ct = 0; ct < 4; ct++) {
        #pragma unroll
        for (int r = 0; r < 4; r++) {
            int m = w * 16 + q * 4 + r;
            xs[m][ct * 16 + l15] = f2bf(acc[ct][r] * diss[m]);
        }
    }
    __syncthreads();
    #pragma unroll
    for (int it = 0; it < 2; it++) {
        int f = it * 256 + tid;
        int r = f >> 3, c = f & 7;
        if (row0 + r < N + 1)   // row N written as zeros (diss=0) -> gather sentinel
            ((uint4*)&h1b[(size_t)(row0 + r) * HID])[c] = *(const uint4*)&xs[r][c * 8];
    }
}

// ---------- fused layer-1 agg + ReLU + W2 GEMM ----------
// 4 nodes/wave (16 lanes each: 2 slots x 8 dim-subs); batch-16 + int4 residual loop.
// Per lane: 1 rowmeta + 2 idx loads + 8 gathers (batch) + residual; shuffle-free dot.
__global__ __launch_bounds__(256) void agg1_fused(
        const int4* __restrict__ rowmeta, const int* __restrict__ csr_src,
        const unsigned short* __restrict__ h1b,
        const float* __restrict__ b1, const float* __restrict__ W2,
        unsigned short* __restrict__ h2b, int N) {
    __shared__ float W2t[NCLS][HID + 4];   // transposed, padded row stride 68
    __shared__ float ts[16][HID];
    int tid = threadIdx.x;
    int w = tid >> 6;
    int lane = tid & 63;
    int quarter = lane >> 4;   // node within wave (0..3)
    int ql = lane & 15;        // lane within node group
    int sub = ql & 7;          // dims sub*8 .. sub*8+7 (16B)
    int slot = ql >> 3;        // edge slot 0..1 (each owns 2 int4 runs = 8 edges)
    int nb = w * 4 + quarter;  // node within block (0..15)
    int n = blockIdx.x * 16 + nb;
    int nc = (n < N) ? n : 0;  // clamp so tail lanes still load safely

    // single 16B rowmeta load + vector index loads BEFORE LDS staging
    int4 meta = rowmeta[nc];
    int start = meta.x;        // 4-aligned by construction
    int plen = meta.y;         // multiple of 4
    float dn = __int_as_float(meta.z);
    const int4* ip = (const int4*)(csr_src + start);
    int4 q0 = ip[2 * slot];
    int4 q1 = ip[2 * slot + 1];

    for (int i = tid; i < HID * NCLS; i += 256) W2t[i & 15][i >> 4] = W2[i];
    __syncthreads();
    if (n >= N) return;        // after the only __syncthreads (no barrier below)

    // vector sentinel-select: plen % 4 == 0, one compare covers a whole int4
    int e0 = slot * 8;
    if (e0 >= plen)     q0 = make_int4(N, N, N, N);
    if (e0 + 4 >= plen) q1 = make_int4(N, N, N, N);
    const unsigned short* hp = h1b + sub * 8;
    uint4 v0 = *(const uint4*)(hp + (unsigned)q0.x * HID);
    uint4 v1 = *(const uint4*)(hp + (unsigned)q0.y * HID);
    uint4 v2 = *(const uint4*)(hp + (unsigned)q0.z * HID);
    uint4 v3 = *(const uint4*)(hp + (unsigned)q0.w * HID);
    uint4 v4 = *(const uint4*)(hp + (unsigned)q1.x * HID);
    uint4 v5 = *(const uint4*)(hp + (unsigned)q1.y * HID);
    uint4 v6 = *(const uint4*)(hp + (unsigned)q1.z * HID);
    uint4 v7 = *(const uint4*)(hp + (unsigned)q1.w * HID);
    f32x2 a0 = (bfpair(v0.x) + bfpair(v1.x)) + (bfpair(v2.x) + bfpair(v3.x));
    f32x2 a1 = (bfpair(v0.y) + bfpair(v1.y)) + (bfpair(v2.y) + bfpair(v3.y));
    f32x2 a2 = (bfpair(v0.z) + bfpair(v1.z)) + (bfpair(v2.z) + bfpair(v3.z));
    f32x2 a3 = (bfpair(v0.w) + bfpair(v1.w)) + (bfpair(v2.w) + bfpair(v3.w));
    a0 += (bfpair(v4.x) + bfpair(v5.x)) + (bfpair(v6.x) + bfpair(v7.x));
    a1 += (bfpair(v4.y) + bfpair(v5.y)) + (bfpair(v6.y) + bfpair(v7.y));
    a2 += (bfpair(v4.z) + bfpair(v5.z)) + (bfpair(v6.z) + bfpair(v7.z));
    a3 += (bfpair(v4.w) + bfpair(v5.w)) + (bfpair(v6.w) + bfpair(v7.w));
    // residual: slots alternate int4 runs past edge 16 (~55% of rows; exec-masked)
    for (int i4 = 4 + slot; i4 * 4 < plen; i4 += 2) {
        int4 qq = ip[i4];
        uint4 r0 = *(const uint4*)(hp + (unsigned)qq.x * HID);
        uint4 r1 = *(const uint4*)(hp + (unsigned)qq.y * HID);
        uint4 r2 = *(const uint4*)(hp + (unsigned)qq.z * HID);
        uint4 r3 = *(const uint4*)(hp + (unsigned)qq.w * HID);
        a0 += (bfpair(r0.x) + bfpair(r1.x)) + (bfpair(r2.x) + bfpair(r3.x));
        a1 += (bfpair(r0.y) + bfpair(r1.y)) + (bfpair(r2.y) + bfpair(r3.y));
        a2 += (bfpair(r0.z) + bfpair(r1.z)) + (bfpair(r2.z) + bfpair(r3.z));
        a3 += (bfpair(r0.w) + bfpair(r1.w)) + (bfpair(r2.w) + bfpair(r3.w));
    }
    // reduce across the 2 slots (lane bit 3 — stays within the node group)
    a0.x += __shfl_xor(a0.x, 8, 64); a0.y += __shfl_xor(a0.y, 8, 64);
    a1.x += __shfl_xor(a1.x, 8, 64); a1.y += __shfl_xor(a1.y, 8, 64);
    a2.x += __shfl_xor(a2.x, 8, 64); a2.y += __shfl_xor(a2.y, 8, 64);
    a3.x += __shfl_xor(a3.x, 8, 64); a3.y += __shfl_xor(a3.y, 8, 64);
    if (slot == 0) {
        float4 bl = ((const float4*)b1)[sub * 2];
        float4 bh = ((const float4*)b1)[sub * 2 + 1];
        float4 r0, r1;
        r0.x = fmaxf(fmaf(dn, a0.x, bl.x), 0.f);
        r0.y = fmaxf(fmaf(dn, a0.y, bl.y), 0.f);
        r0.z = fmaxf(fmaf(dn, a1.x, bl.z), 0.f);
        r0.w = fmaxf(fmaf(dn, a1.y, bl.w), 0.f);
        r1.x = fmaxf(fmaf(dn, a2.x, bh.x), 0.f);
        r1.y = fmaxf(fmaf(dn, a2.y, bh.y), 0.f);
        r1.z = fmaxf(fmaf(dn, a3.x, bh.z), 0.f);
        r1.w = fmaxf(fmaf(dn, a3.y, bh.w), 0.f);
        *(float4*)&ts[nb][sub * 8] = r0;
        *(float4*)&ts[nb][sub * 8 + 4] = r1;
    }
    // wave-local LDS round-trip; each of 16 lanes owns one output class (no shuffle)
    int c = ql;
    const float* tp = &ts[nb][0];
    const float* wp = &W2t[c][0];
    float p = 0.f;
    #pragma unroll
    for (int j = 0; j < 16; j++) {
        float4 tt = *(const float4*)(tp + j * 4);
        float4 uu = *(const float4*)(wp + j * 4);
        p += tt.x * uu.x + tt.y * uu.y + tt.z * uu.z + tt.w * uu.w;
    }
    h2b[(unsigned)n * NCLS + c] = f2bf(p * dn);
}

// ---------- fused layer-2 agg + epilogue ----------
// 8 nodes/wave (8 lanes each: 4 slots x 2 dim-subs); batch-16 + int4 residual loop
__global__ __launch_bounds__(256) void agg2_fused(
        const int4* __restrict__ rowmeta, const int* __restrict__ csr_src,
        const unsigned short* __restrict__ h2b,
        const float* __restrict__ b2, float* __restrict__ out, int N) {
    int t = blockIdx.x * 256 + threadIdx.x;
    int lane = t & 63;
    int grp = lane >> 3;         // node within wave (0..7)
    int gl = lane & 7;
    int slot = gl >> 1;          // edge slot 0..3 (each owns 1 int4 = 4 edges)
    int sub = gl & 1;            // dims sub*8 .. sub*8+7
    int n = (t >> 6) * 8 + grp;
    if (n >= N) return;          // uniform within each 8-lane group
    int4 meta = rowmeta[n];
    int start = meta.x;
    int plen = meta.y;
    float dn = __int_as_float(meta.z);
    const int4* ip = (const int4*)(csr_src + start);
    int4 q0 = ip[slot];
    int e0 = slot * 4;
    if (e0 >= plen) q0 = make_int4(N, N, N, N);   // plen mult of 4: all-or-nothing
    const unsigned short* hp = h2b + sub * 8;
    uint4 v0 = *(const uint4*)(hp + (unsigned)q0.x * NCLS);
    uint4 v1 = *(const uint4*)(hp + (unsigned)q0.y * NCLS);
    uint4 v2 = *(const uint4*)(hp + (unsigned)q0.z * NCLS);
    uint4 v3 = *(const uint4*)(hp + (unsigned)q0.w * NCLS);
    f32x2 a0 = (bfpair(v0.x) + bfpair(v1.x)) + (bfpair(v2.x) + bfpair(v3.x));
    f32x2 a1 = (bfpair(v0.y) + bfpair(v1.y)) + (bfpair(v2.y) + bfpair(v3.y));
    f32x2 a2 = (bfpair(v0.z) + bfpair(v1.z)) + (bfpair(v2.z) + bfpair(v3.z));
    f32x2 a3 = (bfpair(v0.w) + bfpair(v1.w)) + (bfpair(v2.w) + bfpair(v3.w));
    // residual: slots alternate int4 runs past edge 16 (exec-masked)
    for (int i4 = 4 + slot; i4 * 4 < plen; i4 += 4) {
        int4 qq = ip[i4];
        uint4 r0 = *(const uint4*)(hp + (unsigned)qq.x * NCLS);
        uint4 r1 = *(const uint4*)(hp + (unsigned)qq.y * NCLS);
        uint4 r2 = *(const uint4*)(hp + (unsigned)qq.z * NCLS);
        uint4 r3 = *(const uint4*)(hp + (unsigned)qq.w * NCLS);
        a0 += (bfpair(r0.x) + bfpair(r1.x)) + (bfpair(r2.x) + bfpair(r3.x));
        a1 += (bfpair(r0.y) + bfpair(r1.y)) + (bfpair(r2.y) + bfpair(r3.y));
        a2 += (bfpair(r0.z) + bfpair(r1.z)) + (bfpair(r2.z) + bfpair(r3.z));
        a3 += (bfpair(r0.w) + bfpair(r1.w)) + (bfpair(r2.w) + bfpair(r3.w));
    }
    // reduce across 4 slots (lane bits 1,2 — stays inside the 8-lane group)
    #pragma unroll
    for (int m = 2; m <= 4; m <<= 1) {
        a0.x += __shfl_xor(a0.x, m, 64); a0.y += __shfl_xor(a0.y, m, 64);
        a1.x += __shfl_xor(a1.x, m, 64); a1.y += __shfl_xor(a1.y, m, 64);
        a2.x += __shfl_xor(a2.x, m, 64); a2.y += __shfl_xor(a2.y, m, 64);
        a3.x += __shfl_xor(a3.x, m, 64); a3.y += __shfl_xor(a3.y, m, 64);
    }
    if (slot == 0) {
        float4 bl = ((const float4*)b2)[sub * 2];
        float4 bh = ((const float4*)b2)[sub * 2 + 1];
        float4 o0, o1;
        o0.x = fmaf(dn, a0.x, bl.x); o0.y = fmaf(dn, a0.y, bl.y);
        o0.z = fmaf(dn, a1.x, bl.z); o0.w = fmaf(dn, a1.y, bl.w);
        o1.x = fmaf(dn, a2.x, bh.x); o1.y = fmaf(dn, a2.y, bh.y);
        o1.z = fmaf(dn, a3.x, bh.z); o1.w = fmaf(dn, a3.y, bh.w);
        float* op = out + (unsigned)n * NCLS + sub * 8;
        *(float4*)op = o0;
        *(float4*)(op + 4) = o1;
    }
}

extern "C" void kernel_launch(void* const* d_in, const int* in_sizes, int n_in,
                              void* d_out, int out_size, void* d_ws, size_t ws_size,
                              hipStream_t stream) {
    const float* x   = (const float*)d_in[0];
    const int*   src = (const int*)  d_in[1];
    const int*   dst = (const int*)  d_in[2];
    const float* W1  = (const float*)d_in[3];
    const float* b1  = (const float*)d_in[4];
    const float* W2  = (const float*)d_in[5];
    const float* b2  = (const float*)d_in[6];
    float* out = (float*)d_out;
    int E = in_sizes[1];
    int N = in_sizes[0] / F_IN;
    int NB = (N + BNODES - 1) >> BSHIFT;
    int nchunks = (E + CHUNK - 1) / CHUNK;   // 208 for E=1.7M

    char* ws = (char*)d_ws;
    size_t off = 0;
    auto alloc = [&](size_t bytes) { size_t o = off; off = (off + bytes + 255) & ~(size_t)255; return (void*)(ws + o); };
    int*   bucket_cursor = (int*)  alloc((size_t)NB * 4);
    int4*  rowmeta       = (int4*) alloc((size_t)N * 16);
    int*   csr_src       = (int*)  alloc((size_t)NB * CAPP * 4);   // fixed-stride padded CSR
    float* dis           = (float*)alloc((size_t)N * 4);
    unsigned short* w1t  = (unsigned short*)alloc((size_t)F_IN * HID * 2);
    size_t h1b_bytes  = (size_t)(N + 1) * HID * 2;                 // 12.80 MB
    size_t part_bytes = (size_t)NB * CAP * 4;                      // 12.81 MB
    unsigned short* h1b  = (unsigned short*)alloc(h1b_bytes > part_bytes ? h1b_bytes : part_bytes);
    unsigned short* h2b  = (unsigned short*)alloc((size_t)(N + 1) * NCLS * 2); // +1 sentinel row
    // part[] aliases h1b: dead before gemm1 writes h1b (alloc = max of both sizes)
    unsigned int* part   = (unsigned int*)h1b;

    hipMemsetAsync(bucket_cursor, 0, (size_t)NB * 4, stream);  // capture-legal memset node
    w1t_kernel     <<<1, 256, 0, stream>>>(W1, w1t, h2b, N);
    scatter_kernel <<<nchunks, 256, 0, stream>>>(src, dst, bucket_cursor, part, E, NB);
    csr_build      <<<NB, 512, 0, stream>>>(part, bucket_cursor, csr_src, rowmeta, dis, N);
    gemm1_kernel   <<<(N + 64) / 64, 256, 0, stream>>>(x, w1t, dis, h1b, N);  // +1 covers row N
    agg1_fused     <<<(N + 15) / 16, 256, 0, stream>>>(rowmeta, csr_src, h1b, b1, W2, h2b, N);
    agg2_fused     <<<(N + 31) / 32, 256, 0, stream>>>(rowmeta, csr_src, h2b, b2, out, N);
}